// Round 3
// baseline (39722.458 us; speedup 1.0000x reference)
//
#include <hip/hip_runtime.h>
#include <hip/hip_bf16.h>
#include <hip/hip_cooperative_groups.h>

namespace cg = cooperative_groups;

using bf16 = __hip_bfloat16;

typedef __attribute__((ext_vector_type(8))) short short8;
typedef __attribute__((ext_vector_type(4))) float floatx4;

static constexpr int B_ = 256;   // batch
static constexpr int T_ = 128;   // time steps
static constexpr int CH = 32;    // time-chunk (history buffers sized to this)

__device__ __forceinline__ float bf2f(bf16 v) { return __bfloat162float(v); }
__device__ __forceinline__ bf16  f2bf(float v) { return __float2bfloat16(v); }

// round row bytes up to a multiple of 128 so the XOR swizzle (flips byte
// bits 4..6, i.e. permutes 16B blocks within a 128B stripe) stays in-row.
constexpr size_t row_bytes(int kres) { return ((size_t)kres * 2 + 127) & ~(size_t)127; }

// ---------------------------------------------------------------- fp32->bf16
__global__ __launch_bounds__(256) void cvt_k(const float* __restrict__ src,
                                             bf16* __restrict__ dst, int n8)
{
    int i = blockIdx.x * 256 + threadIdx.x;
    if (i >= n8) return;
    const float* s = src + (size_t)i * 8;
    float4 a = *(const float4*)s;
    float4 b = *(const float4*)(s + 4);
    bf16 t[8] = {f2bf(a.x), f2bf(a.y), f2bf(a.z), f2bf(a.w),
                 f2bf(b.x), f2bf(b.y), f2bf(b.z), f2bf(b.w)};
    *(uint4*)(dst + (size_t)i * 8) = *(uint4*)t;
}

// ------------------------------------------------------------------ embedding
// emb_all[t][b][0:32] = bf16(emb_table[seq[b][t]])
__global__ __launch_bounds__(256) void embed_k(const int* __restrict__ seq,
                                               const float* __restrict__ tab,
                                               bf16* __restrict__ emb_all)
{
    int c = blockIdx.x * 256 + threadIdx.x;  // T_*B_*4 chunks of 8 elems
    int t = c >> 10;                         // B_*4 = 1024 chunks per step
    int r = c & 1023;
    int b = r >> 2, i = r & 3;
    int tok = seq[b * T_ + t];
    const float* s = tab + (size_t)tok * 32 + i * 8;
    bf16 tmp[8];
#pragma unroll
    for (int j = 0; j < 8; ++j) tmp[j] = f2bf(s[j]);
    *(uint4*)(emb_all + ((size_t)t * B_ + b) * 32 + i * 8) = *(uint4*)tmp;
}

// ----------------------------------------------------- fp32 -> bf16 transpose
// out[n][k] = bf16(in[k][n]),  k < K, n < N   (in has leading dim ldin)
__global__ __launch_bounds__(256) void transpose_bf16_k(
    const float* __restrict__ in, int ldin, bf16* __restrict__ out, int K, int N)
{
    __shared__ float tile[32][33];
    const int bk = blockIdx.x * 32, bn = blockIdx.y * 32;
    const int tx = threadIdx.x & 31, ty = threadIdx.x >> 5;  // 32 x 8
#pragma unroll
    for (int i = 0; i < 32; i += 8)
        tile[ty + i][tx] = in[(size_t)(bk + ty + i) * ldin + (bn + tx)];
    __syncthreads();
#pragma unroll
    for (int i = 0; i < 32; i += 8)
        out[(size_t)(bn + ty + i) * K + (bk + tx)] = f2bf(tile[tx][ty + i]);
}

// ------------------------------------------------------------------- concat
// cc[b][0:3584] = bf16(concat(h0[b], h1[b], h2[b]))
__global__ __launch_bounds__(256) void concat_k(const float* __restrict__ h0,
                                                const float* __restrict__ h1,
                                                const float* __restrict__ h2,
                                                bf16* __restrict__ cc)
{
    int c = blockIdx.x * 256 + threadIdx.x;  // 256*448 chunks of 8
    int b = c / 448;
    int j = (c % 448) * 8;
    const float* src;
    if (j < 512)        src = h0 + (size_t)b * 512 + j;
    else if (j < 1536)  src = h1 + (size_t)b * 1024 + (j - 512);
    else                src = h2 + (size_t)b * 2048 + (j - 1536);
    bf16 tmp[8];
#pragma unroll
    for (int i = 0; i < 8; ++i) tmp[i] = f2bf(src[i]);
    *(uint4*)(cc + (size_t)b * 3584 + j) = *(uint4*)tmp;
}

// --------------------------------------------------------------- final dense
// y = tanh(cc @ dw + db), M=256, K=3584, N=512. 64x64 tile, grid (8,4).
__global__ __launch_bounds__(256) void dense_k(const bf16* __restrict__ A,
                                               const bf16* __restrict__ Bw,
                                               const bf16* __restrict__ bias,
                                               float* __restrict__ yout)
{
    __shared__ __align__(16) bf16 As[64 * 40];
    __shared__ __align__(16) bf16 Bs[64 * 40];

    const int tid  = threadIdx.x;
    const int bm   = blockIdx.y * 64;
    const int bn   = blockIdx.x * 64;
    const int lane = tid & 63;
    const int wave = tid >> 6;
    const int wm   = (wave >> 1) * 32;
    const int wn   = (wave & 1) * 32;
    const int quad = lane >> 4;
    const int l16  = lane & 15;

    floatx4 acc[2][2] = {};

    const int ar = tid >> 2, ak = (tid & 3) * 8;
    const int bk = tid >> 3, bn0 = (tid & 7) * 8;

    for (int k0 = 0; k0 < 3584; k0 += 32) {
        uint4 av = *(const uint4*)(A + (size_t)(bm + ar) * 3584 + k0 + ak);
        *(uint4*)&As[ar * 40 + ak] = av;
        uint4 bv = *(const uint4*)(Bw + (size_t)(k0 + bk) * 512 + bn + bn0);
        bf16 tmp[8];
        *(uint4*)tmp = bv;
#pragma unroll
        for (int i = 0; i < 8; ++i) Bs[(bn0 + i) * 40 + bk] = tmp[i];
        __syncthreads();

        short8 af0 = *(const short8*)&As[(wm + l16) * 40 + quad * 8];
        short8 af1 = *(const short8*)&As[(wm + 16 + l16) * 40 + quad * 8];
        short8 bw0 = *(const short8*)&Bs[(wn + l16) * 40 + quad * 8];
        short8 bw1 = *(const short8*)&Bs[(wn + 16 + l16) * 40 + quad * 8];

        acc[0][0] = __builtin_amdgcn_mfma_f32_16x16x32_bf16(af0, bw0, acc[0][0], 0, 0, 0);
        acc[0][1] = __builtin_amdgcn_mfma_f32_16x16x32_bf16(af0, bw1, acc[0][1], 0, 0, 0);
        acc[1][0] = __builtin_amdgcn_mfma_f32_16x16x32_bf16(af1, bw0, acc[1][0], 0, 0, 0);
        acc[1][1] = __builtin_amdgcn_mfma_f32_16x16x32_bf16(af1, bw1, acc[1][1], 0, 0, 0);
        __syncthreads();
    }

#pragma unroll
    for (int tm = 0; tm < 2; ++tm)
#pragma unroll
        for (int tn = 0; tn < 2; ++tn)
#pragma unroll
            for (int r = 0; r < 4; ++r) {
                const int row = bm + wm + tm * 16 + quad * 4 + r;
                const int col = bn + wn + tn * 16 + l16;
                float v = acc[tm][tn][r] + bf2f(bias[col]);
                yout[(size_t)row * 512 + col] = tanhf(v);
            }
}

// =================================================================
// Persistent GRU layer over a time chunk [t0, t1).
// 256 WGs x 512 threads, 1 WG/CU. Each WG owns a 16-column slice of
// the gates matrix and a 16-column slice of the candidate matrix,
// resident in LDS (XOR-swizzled, stripe-safe) for the whole chunk.
// For the largest layer (STREAM_X) only h-part weights are resident;
// x-part weights stream from a pre-transposed bf16 copy in global.
// =================================================================
template <int IN, int OUT, bool STREAM_X, bool WRITE_ALL>
__global__ __launch_bounds__(512) void gru_layer_k(
    const bf16* __restrict__ Xall,   // chunk input history, bf16
    const float* __restrict__ gkF,   // [(IN+OUT)][2*OUT] fp32
    const float* __restrict__ gbF,   // [2*OUT]
    const float* __restrict__ ckF,   // [(IN+OUT)][OUT]
    const float* __restrict__ cbF,   // [OUT]
    const bf16* __restrict__ WgxT,   // [2*OUT][IN] bf16 (x-part, STREAM_X only)
    const bf16* __restrict__ WcxT,   // [OUT][IN]   bf16 (x-part, STREAM_X only)
    const int* __restrict__ lens,
    float* __restrict__ hF,          // [256][OUT] fp32 master state
    bf16* __restrict__ hB,           // [256][OUT] bf16 state
    bf16* __restrict__ rhB,          // [256][OUT] bf16 r*h
    float* __restrict__ zbF,         // [256][OUT] fp32 z
    bf16* __restrict__ Hall,         // [t1-t0][256][OUT] (WRITE_ALL only)
    int t0, int t1, int xbase)
{
    constexpr int NG = 2 * OUT, NC = OUT;
    constexpr int KRES = STREAM_X ? OUT : (IN + OUT);   // LDS-resident K
    constexpr int NWG = NG / 16, MSG = 256 / NWG, MRG = 256 / MSG, FG = MRG / 16;
    constexpr int NWC = NC / 16, MSC = 256 / NWC, MRC = 256 / MSC, FC = MRC / 16;
    constexpr int FPW = (FG >= 8) ? (FG / 8) : 1;       // gate frags per wave
    constexpr size_t ROWB = row_bytes(KRES);            // LDS row bytes (128-mult)
    constexpr int KH0 = STREAM_X ? 0 : IN;              // h-part offset in LDS

    extern __shared__ char lds[];
    char* Wg = lds;
    char* Wc = lds + (size_t)16 * ROWB;

    const int tid  = threadIdx.x;
    const int wgid = blockIdx.x;
    const int wv   = tid >> 6;
    const int lane = tid & 63;
    const int l16  = lane & 15;
    const int quad = lane >> 4;

    const int cgG = wgid / MSG, mbG = wgid % MSG;   // gates col-group / m-band
    const int cgC = wgid / MSC, mbC = wgid % MSC;   // cand  col-group / m-band

    // ---- load resident weight slices into LDS (swizzled [16][KRES]) ----
    {
        const int colG = cgG * 16;
        for (int idx = tid; idx < 16 * KRES; idx += 512) {
            const int n = idx & 15, k = idx >> 4;
            const int srow = STREAM_X ? (IN + k) : k;
            bf16 v = f2bf(gkF[(size_t)srow * NG + colG + n]);
            *(bf16*)(Wg + (size_t)n * ROWB + ((k * 2) ^ ((n & 7) << 4))) = v;
        }
        const int colC = cgC * 16;
        for (int idx = tid; idx < 16 * KRES; idx += 512) {
            const int n = idx & 15, k = idx >> 4;
            const int srow = STREAM_X ? (IN + k) : k;
            bf16 v = f2bf(ckF[(size_t)srow * NC + colC + n]);
            *(bf16*)(Wc + (size_t)n * ROWB + ((k * 2) ^ ((n & 7) << 4))) = v;
        }
    }
    __syncthreads();

    cg::grid_group grid = cg::this_grid();

    const bool actG = (wv * FPW) < FG;
    const bool actC = wv < FC;
    const int  swz  = (l16 & 7) << 4;

    for (int t = t0; t < t1; ++t) {
        const bf16* xb = Xall + (size_t)(t - xbase) * 256 * IN;
        // ======================= gates =======================
        if (actG) {
            floatx4 acc[FPW] = {};
            int rowA[FPW];
#pragma unroll
            for (int j = 0; j < FPW; ++j)
                rowA[j] = mbG * MRG + (wv * FPW + j) * 16 + l16;

            // x-part of K
#pragma unroll 4
            for (int kb = 0; kb < IN / 32; ++kb) {
                short8 b;
                if constexpr (STREAM_X)
                    b = *(const short8*)(WgxT + (size_t)(cgG * 16 + l16) * IN + kb * 32 + quad * 8);
                else
                    b = *(const short8*)(Wg + (size_t)l16 * ROWB + ((kb * 64 + quad * 16) ^ swz));
#pragma unroll
                for (int j = 0; j < FPW; ++j) {
                    short8 a = *(const short8*)(xb + (size_t)rowA[j] * IN + kb * 32 + quad * 8);
                    acc[j] = __builtin_amdgcn_mfma_f32_16x16x32_bf16(a, b, acc[j], 0, 0, 0);
                }
            }
            // h-part of K
#pragma unroll 4
            for (int kb = 0; kb < OUT / 32; ++kb) {
                short8 b = *(const short8*)(Wg + (size_t)l16 * ROWB +
                                            ((KH0 * 2 + kb * 64 + quad * 16) ^ swz));
#pragma unroll
                for (int j = 0; j < FPW; ++j) {
                    short8 a = *(const short8*)(hB + (size_t)rowA[j] * OUT + kb * 32 + quad * 8);
                    acc[j] = __builtin_amdgcn_mfma_f32_16x16x32_bf16(a, b, acc[j], 0, 0, 0);
                }
            }
            // epilogue: sigmoid; r-half -> rh = r*h, z-half -> zb
            const int col   = cgG * 16 + l16;
            const float bia = gbF[col];
            const bool isR  = (cgG * 16) < OUT;   // WG-uniform
#pragma unroll
            for (int j = 0; j < FPW; ++j) {
#pragma unroll
                for (int r = 0; r < 4; ++r) {
                    const int row = mbG * MRG + (wv * FPW + j) * 16 + quad * 4 + r;
                    float v = acc[j][r] + bia;
                    float s = 1.f / (1.f + __expf(-v));
                    if (isR) {
                        size_t idx = (size_t)row * OUT + col;
                        rhB[idx] = f2bf(s * hF[idx]);
                    } else {
                        zbF[(size_t)row * OUT + (col - OUT)] = s;
                    }
                }
            }
        }
        grid.sync();

        // ===================== candidate =====================
        if (actC) {
            floatx4 acc = {};
            const int rowA = mbC * MRC + wv * 16 + l16;

#pragma unroll 4
            for (int kb = 0; kb < IN / 32; ++kb) {
                short8 b;
                if constexpr (STREAM_X)
                    b = *(const short8*)(WcxT + (size_t)(cgC * 16 + l16) * IN + kb * 32 + quad * 8);
                else
                    b = *(const short8*)(Wc + (size_t)l16 * ROWB + ((kb * 64 + quad * 16) ^ swz));
                short8 a = *(const short8*)(xb + (size_t)rowA * IN + kb * 32 + quad * 8);
                acc = __builtin_amdgcn_mfma_f32_16x16x32_bf16(a, b, acc, 0, 0, 0);
            }
#pragma unroll 4
            for (int kb = 0; kb < OUT / 32; ++kb) {
                short8 b = *(const short8*)(Wc + (size_t)l16 * ROWB +
                                            ((KH0 * 2 + kb * 64 + quad * 16) ^ swz));
                short8 a = *(const short8*)(rhB + (size_t)rowA * OUT + kb * 32 + quad * 8);
                acc = __builtin_amdgcn_mfma_f32_16x16x32_bf16(a, b, acc, 0, 0, 0);
            }
            const int col   = cgC * 16 + l16;
            const float bia = cbF[col];
#pragma unroll
            for (int r = 0; r < 4; ++r) {
                const int row = mbC * MRC + wv * 16 + quad * 4 + r;
                float v = acc[r] + bia;
                float c = tanhf(v);
                size_t idx = (size_t)row * OUT + col;
                float z = zbF[idx], ho = hF[idx];
                float hn = (t < lens[row]) ? (z * ho + (1.f - z) * c) : ho;
                hF[idx] = hn;
                bf16 hv = f2bf(hn);
                hB[idx] = hv;
                if constexpr (WRITE_ALL)
                    Hall[(size_t)(t - t0) * 256 * OUT + idx] = hv;
            }
        }
        grid.sync();
    }
}

// =================================================================
extern "C" void kernel_launch(void* const* d_in, const int* in_sizes, int n_in,
                              void* d_out, int out_size, void* d_ws, size_t ws_size,
                              hipStream_t stream)
{
    (void)in_sizes; (void)n_in; (void)out_size; (void)ws_size;

    const int*   seq  = (const int*)d_in[0];
    const int*   lens = (const int*)d_in[1];
    const float* tab  = (const float*)d_in[2];
    const float* gkF[3] = {(const float*)d_in[3], (const float*)d_in[7], (const float*)d_in[11]};
    const float* gbF[3] = {(const float*)d_in[4], (const float*)d_in[8], (const float*)d_in[12]};
    const float* ckF[3] = {(const float*)d_in[5], (const float*)d_in[9], (const float*)d_in[13]};
    const float* cbF[3] = {(const float*)d_in[6], (const float*)d_in[10], (const float*)d_in[14]};
    const float* dwF = (const float*)d_in[15];
    const float* dbF = (const float*)d_in[16];
    float* y = (float*)d_out;

    const int outs[3] = {512, 1024, 2048};

    char* w = (char*)d_ws;
    auto alloc = [&](size_t bytes) -> void* {
        void* p = (void*)w;
        w += (bytes + 255) & ~(size_t)255;
        return p;
    };

    // workspace (total ~56 MB — inside the round-0-proven ~68 MB budget)
    bf16* WgxT    = (bf16*)alloc((size_t)4096 * 1024 * sizeof(bf16));
    bf16* WcxT    = (bf16*)alloc((size_t)2048 * 1024 * sizeof(bf16));
    bf16* emb_all = (bf16*)alloc((size_t)T_ * B_ * 32 * sizeof(bf16));
    bf16* H0c     = (bf16*)alloc((size_t)CH * B_ * 512 * sizeof(bf16));
    bf16* H1c     = (bf16*)alloc((size_t)CH * B_ * 1024 * sizeof(bf16));
    float* hf[3]; bf16* hb[3]; bf16* rh[3]; float* zb[3];
    for (int l = 0; l < 3; ++l) {
        hf[l] = (float*)alloc((size_t)B_ * outs[l] * sizeof(float));
        hb[l] = (bf16*)alloc((size_t)B_ * outs[l] * sizeof(bf16));
        rh[l] = (bf16*)alloc((size_t)B_ * outs[l] * sizeof(bf16));
        zb[l] = (float*)alloc((size_t)B_ * outs[l] * sizeof(float));
    }
    bf16* dw = (bf16*)alloc((size_t)3584 * 512 * sizeof(bf16));
    bf16* db = (bf16*)alloc((size_t)512 * sizeof(bf16));
    bf16* cc = (bf16*)alloc((size_t)B_ * 3584 * sizeof(bf16));

    auto kL0 = gru_layer_k<32,   512,  false, true>;
    auto kL1 = gru_layer_k<512,  1024, false, true>;
    auto kL2 = gru_layer_k<1024, 2048, true,  false>;
    const unsigned lds0 = (unsigned)(2 * 16 * row_bytes(32 + 512));     //  36,864 B
    const unsigned lds1 = (unsigned)(2 * 16 * row_bytes(512 + 1024));   //  98,304 B
    const unsigned lds2 = (unsigned)(2 * 16 * row_bytes(2048));         // 131,072 B

    hipFuncSetAttribute((const void*)kL0, hipFuncAttributeMaxDynamicSharedMemorySize, (int)lds0);
    hipFuncSetAttribute((const void*)kL1, hipFuncAttributeMaxDynamicSharedMemorySize, (int)lds1);
    hipFuncSetAttribute((const void*)kL2, hipFuncAttributeMaxDynamicSharedMemorySize, (int)lds2);

    // ---- prep ----
    {   // dense weights to bf16
        int n8 = 3584 * 512 / 8;
        cvt_k<<<(n8 + 255) / 256, 256, 0, stream>>>(dwF, dw, n8);
        cvt_k<<<1, 256, 0, stream>>>(dbF, db, 512 / 8);
    }
    embed_k<<<T_ * B_ * 4 / 256, 256, 0, stream>>>(seq, tab, emb_all);
    // layer-2 x-part weights, transposed bf16 (k<1024 rows of gk2/ck2)
    transpose_bf16_k<<<dim3(1024 / 32, 4096 / 32), 256, 0, stream>>>(gkF[2], 4096, WgxT, 1024, 4096);
    transpose_bf16_k<<<dim3(1024 / 32, 2048 / 32), 256, 0, stream>>>(ckF[2], 2048, WcxT, 1024, 2048);

    for (int l = 0; l < 3; ++l) {
        hipMemsetAsync(hf[l], 0, (size_t)B_ * outs[l] * sizeof(float), stream);
        hipMemsetAsync(hb[l], 0, (size_t)B_ * outs[l] * sizeof(bf16), stream);
    }

    // ---- recurrent layers: 32-step chunks, L0 -> L1 -> L2 per chunk ----
    for (int c = 0; c < T_ / CH; ++c) {
        int t0 = c * CH, t1 = t0 + CH;
        {
            const bf16* xall = emb_all;
            const float *g = gkF[0], *gb_ = gbF[0], *cw = ckF[0], *cb_ = cbF[0];
            const bf16 *wgx = nullptr, *wcx = nullptr;
            float* hf_ = hf[0]; bf16* hb_ = hb[0]; bf16* rh_ = rh[0]; float* zb_ = zb[0];
            bf16* hall = H0c; int xb = 0;
            void* args[] = {&xall, &g, &gb_, &cw, &cb_, &wgx, &wcx, (void*)&lens,
                            &hf_, &hb_, &rh_, &zb_, &hall, &t0, &t1, &xb};
            hipLaunchCooperativeKernel((const void*)kL0, dim3(256), dim3(512), args, lds0, stream);
        }
        {
            const bf16* xall = H0c;
            const float *g = gkF[1], *gb_ = gbF[1], *cw = ckF[1], *cb_ = cbF[1];
            const bf16 *wgx = nullptr, *wcx = nullptr;
            float* hf_ = hf[1]; bf16* hb_ = hb[1]; bf16* rh_ = rh[1]; float* zb_ = zb[1];
            bf16* hall = H1c; int xb = t0;
            void* args[] = {&xall, &g, &gb_, &cw, &cb_, &wgx, &wcx, (void*)&lens,
                            &hf_, &hb_, &rh_, &zb_, &hall, &t0, &t1, &xb};
            hipLaunchCooperativeKernel((const void*)kL1, dim3(256), dim3(512), args, lds1, stream);
        }
        {
            const bf16* xall = H1c;
            const float *g = gkF[2], *gb_ = gbF[2], *cw = ckF[2], *cb_ = cbF[2];
            const bf16 *wgx = WgxT, *wcx = WcxT;
            float* hf_ = hf[2]; bf16* hb_ = hb[2]; bf16* rh_ = rh[2]; float* zb_ = zb[2];
            bf16* hall = nullptr; int xb = t0;
            void* args[] = {&xall, &g, &gb_, &cw, &cb_, &wgx, &wcx, (void*)&lens,
                            &hf_, &hb_, &rh_, &zb_, &hall, &t0, &t1, &xb};
            hipLaunchCooperativeKernel((const void*)kL2, dim3(256), dim3(512), args, lds2, stream);
        }
    }

    // ---- head ----
    concat_k<<<B_ * 3584 / 8 / 256, 256, 0, stream>>>(hf[0], hf[1], hf[2], cc);
    dense_k<<<dim3(512 / 64, 256 / 64), 256, 0, stream>>>(cc, dw, db, y);
}

// Round 4
// 26748.703 us; speedup vs baseline: 1.4850x; 1.4850x over previous
//
#include <hip/hip_runtime.h>
#include <hip/hip_bf16.h>

using bf16 = __hip_bfloat16;

typedef __attribute__((ext_vector_type(8))) short short8;
typedef __attribute__((ext_vector_type(4))) float floatx4;

static constexpr int B_ = 256;   // batch
static constexpr int T_ = 128;   // time steps
static constexpr int CH = 32;    // time-chunk (history buffers sized to this)

__device__ __forceinline__ float bf2f(bf16 v) { return __bfloat162float(v); }
__device__ __forceinline__ bf16  f2bf(float v) { return __float2bfloat16(v); }

// round row bytes up to a multiple of 128 so the XOR swizzle (flips byte
// bits 4..6, i.e. permutes 16B blocks within a 128B stripe) stays in-row.
constexpr size_t row_bytes(int kres) { return ((size_t)kres * 2 + 127) & ~(size_t)127; }

// ---------------- device-coherent access helpers (cross-XCD, no L2 flush) ----
// Stores: write-through to the device coherence point (sc0 sc1).
// Loads: agent-scope relaxed atomics -> global_load ... sc1 (bypass stale L2).
__device__ __forceinline__ void cstore_f32(float* p, float v) {
    asm volatile("global_store_dword %0, %1, off sc0 sc1" :: "v"(p), "v"(v) : "memory");
}
__device__ __forceinline__ void cstore_bf16(bf16* p, float v) {
    bf16 b = f2bf(v);
    unsigned u = *(unsigned short*)&b;
    asm volatile("global_store_short %0, %1, off sc0 sc1" :: "v"(p), "v"(u) : "memory");
}
__device__ __forceinline__ float cload_f32(const float* p) {
    unsigned v = __hip_atomic_load((const unsigned*)p, __ATOMIC_RELAXED, __HIP_MEMORY_SCOPE_AGENT);
    return __uint_as_float(v);
}
__device__ __forceinline__ short8 cload8(const bf16* p) {
    union { unsigned long long q[2]; short8 v; } u;
    const unsigned long long* pp = (const unsigned long long*)p;
    u.q[0] = __hip_atomic_load(pp,     __ATOMIC_RELAXED, __HIP_MEMORY_SCOPE_AGENT);
    u.q[1] = __hip_atomic_load(pp + 1, __ATOMIC_RELAXED, __HIP_MEMORY_SCOPE_AGENT);
    return u.v;
}

// Lightweight device-wide barrier: no L2 writeback/invalidate.
// Every wave drains its (write-through) stores, then block leaders count up.
__device__ __forceinline__ void dev_barrier(unsigned* ctr, unsigned target) {
    asm volatile("s_waitcnt vmcnt(0)" ::: "memory");
    __syncthreads();
    if (threadIdx.x == 0) {
        __hip_atomic_fetch_add(ctr, 1u, __ATOMIC_RELAXED, __HIP_MEMORY_SCOPE_AGENT);
        while (__hip_atomic_load(ctr, __ATOMIC_RELAXED, __HIP_MEMORY_SCOPE_AGENT) < target)
            __builtin_amdgcn_s_sleep(2);
        asm volatile("" ::: "memory");
    }
    __syncthreads();
}

// ---------------------------------------------------------------- fp32->bf16
__global__ __launch_bounds__(256) void cvt_k(const float* __restrict__ src,
                                             bf16* __restrict__ dst, int n8)
{
    int i = blockIdx.x * 256 + threadIdx.x;
    if (i >= n8) return;
    const float* s = src + (size_t)i * 8;
    float4 a = *(const float4*)s;
    float4 b = *(const float4*)(s + 4);
    bf16 t[8] = {f2bf(a.x), f2bf(a.y), f2bf(a.z), f2bf(a.w),
                 f2bf(b.x), f2bf(b.y), f2bf(b.z), f2bf(b.w)};
    *(uint4*)(dst + (size_t)i * 8) = *(uint4*)t;
}

// ------------------------------------------------------------------ embedding
__global__ __launch_bounds__(256) void embed_k(const int* __restrict__ seq,
                                               const float* __restrict__ tab,
                                               bf16* __restrict__ emb_all)
{
    int c = blockIdx.x * 256 + threadIdx.x;
    int t = c >> 10;
    int r = c & 1023;
    int b = r >> 2, i = r & 3;
    int tok = seq[b * T_ + t];
    const float* s = tab + (size_t)tok * 32 + i * 8;
    bf16 tmp[8];
#pragma unroll
    for (int j = 0; j < 8; ++j) tmp[j] = f2bf(s[j]);
    *(uint4*)(emb_all + ((size_t)t * B_ + b) * 32 + i * 8) = *(uint4*)tmp;
}

// ----------------------------------------------------- fp32 -> bf16 transpose
__global__ __launch_bounds__(256) void transpose_bf16_k(
    const float* __restrict__ in, int ldin, bf16* __restrict__ out, int K, int N)
{
    __shared__ float tile[32][33];
    const int bk = blockIdx.x * 32, bn = blockIdx.y * 32;
    const int tx = threadIdx.x & 31, ty = threadIdx.x >> 5;
#pragma unroll
    for (int i = 0; i < 32; i += 8)
        tile[ty + i][tx] = in[(size_t)(bk + ty + i) * ldin + (bn + tx)];
    __syncthreads();
#pragma unroll
    for (int i = 0; i < 32; i += 8)
        out[(size_t)(bn + ty + i) * K + (bk + tx)] = f2bf(tile[tx][ty + i]);
}

// ------------------------------------------------------------------- concat
__global__ __launch_bounds__(256) void concat_k(const float* __restrict__ h0,
                                                const float* __restrict__ h1,
                                                const float* __restrict__ h2,
                                                bf16* __restrict__ cc)
{
    int c = blockIdx.x * 256 + threadIdx.x;
    int b = c / 448;
    int j = (c % 448) * 8;
    const float* src;
    if (j < 512)        src = h0 + (size_t)b * 512 + j;
    else if (j < 1536)  src = h1 + (size_t)b * 1024 + (j - 512);
    else                src = h2 + (size_t)b * 2048 + (j - 1536);
    bf16 tmp[8];
#pragma unroll
    for (int i = 0; i < 8; ++i) tmp[i] = f2bf(src[i]);
    *(uint4*)(cc + (size_t)b * 3584 + j) = *(uint4*)tmp;
}

// --------------------------------------------------------------- final dense
__global__ __launch_bounds__(256) void dense_k(const bf16* __restrict__ A,
                                               const bf16* __restrict__ Bw,
                                               const bf16* __restrict__ bias,
                                               float* __restrict__ yout)
{
    __shared__ __align__(16) bf16 As[64 * 40];
    __shared__ __align__(16) bf16 Bs[64 * 40];

    const int tid  = threadIdx.x;
    const int bm   = blockIdx.y * 64;
    const int bn   = blockIdx.x * 64;
    const int lane = tid & 63;
    const int wave = tid >> 6;
    const int wm   = (wave >> 1) * 32;
    const int wn   = (wave & 1) * 32;
    const int quad = lane >> 4;
    const int l16  = lane & 15;

    floatx4 acc[2][2] = {};

    const int ar = tid >> 2, ak = (tid & 3) * 8;
    const int bk = tid >> 3, bn0 = (tid & 7) * 8;

    for (int k0 = 0; k0 < 3584; k0 += 32) {
        uint4 av = *(const uint4*)(A + (size_t)(bm + ar) * 3584 + k0 + ak);
        *(uint4*)&As[ar * 40 + ak] = av;
        uint4 bv = *(const uint4*)(Bw + (size_t)(k0 + bk) * 512 + bn + bn0);
        bf16 tmp[8];
        *(uint4*)tmp = bv;
#pragma unroll
        for (int i = 0; i < 8; ++i) Bs[(bn0 + i) * 40 + bk] = tmp[i];
        __syncthreads();

        short8 af0 = *(const short8*)&As[(wm + l16) * 40 + quad * 8];
        short8 af1 = *(const short8*)&As[(wm + 16 + l16) * 40 + quad * 8];
        short8 bw0 = *(const short8*)&Bs[(wn + l16) * 40 + quad * 8];
        short8 bw1 = *(const short8*)&Bs[(wn + 16 + l16) * 40 + quad * 8];

        acc[0][0] = __builtin_amdgcn_mfma_f32_16x16x32_bf16(af0, bw0, acc[0][0], 0, 0, 0);
        acc[0][1] = __builtin_amdgcn_mfma_f32_16x16x32_bf16(af0, bw1, acc[0][1], 0, 0, 0);
        acc[1][0] = __builtin_amdgcn_mfma_f32_16x16x32_bf16(af1, bw0, acc[1][0], 0, 0, 0);
        acc[1][1] = __builtin_amdgcn_mfma_f32_16x16x32_bf16(af1, bw1, acc[1][1], 0, 0, 0);
        __syncthreads();
    }

#pragma unroll
    for (int tm = 0; tm < 2; ++tm)
#pragma unroll
        for (int tn = 0; tn < 2; ++tn)
#pragma unroll
            for (int r = 0; r < 4; ++r) {
                const int row = bm + wm + tm * 16 + quad * 4 + r;
                const int col = bn + wn + tn * 16 + l16;
                float v = acc[tm][tn][r] + bf2f(bias[col]);
                yout[(size_t)row * 512 + col] = tanhf(v);
            }
}

// =================================================================
// Persistent GRU layer over a time chunk [t0, t1).
// Same structure as round 3, but grid.sync() is replaced by a
// lightweight barrier (no L2 flush); all cross-WG mutable state
// (hB, rhB, zbF, hF) uses device-coherent loads/stores so per-XCD
// L2 stays warm with weights and x-tiles for the whole dispatch.
// =================================================================
template <int IN, int OUT, bool STREAM_X, bool WRITE_ALL>
__global__ __launch_bounds__(512) void gru_layer_k(
    const bf16* __restrict__ Xall,
    const float* __restrict__ gkF,
    const float* __restrict__ gbF,
    const float* __restrict__ ckF,
    const float* __restrict__ cbF,
    const bf16* __restrict__ WgxT,
    const bf16* __restrict__ WcxT,
    const int* __restrict__ lens,
    float* __restrict__ hF,
    bf16* __restrict__ hB,
    bf16* __restrict__ rhB,
    float* __restrict__ zbF,
    bf16* __restrict__ Hall,
    unsigned* __restrict__ bar_ctr,
    int t0, int t1, int xbase)
{
    constexpr int NG = 2 * OUT, NC = OUT;
    constexpr int KRES = STREAM_X ? OUT : (IN + OUT);
    constexpr int NWG = NG / 16, MSG = 256 / NWG, MRG = 256 / MSG, FG = MRG / 16;
    constexpr int NWC = NC / 16, MSC = 256 / NWC, MRC = 256 / MSC, FC = MRC / 16;
    constexpr int FPW = (FG >= 8) ? (FG / 8) : 1;
    constexpr size_t ROWB = row_bytes(KRES);
    constexpr int KH0 = STREAM_X ? 0 : IN;

    extern __shared__ char lds[];
    char* Wg = lds;
    char* Wc = lds + (size_t)16 * ROWB;

    const int tid  = threadIdx.x;
    const int wgid = blockIdx.x;
    const int wv   = tid >> 6;
    const int lane = tid & 63;
    const int l16  = lane & 15;
    const int quad = lane >> 4;

    const int cgG = wgid / MSG, mbG = wgid % MSG;
    const int cgC = wgid / MSC, mbC = wgid % MSC;

    // ---- load resident weight slices into LDS (swizzled [16][KRES]) ----
    {
        const int colG = cgG * 16;
        for (int idx = tid; idx < 16 * KRES; idx += 512) {
            const int n = idx & 15, k = idx >> 4;
            const int srow = STREAM_X ? (IN + k) : k;
            bf16 v = f2bf(gkF[(size_t)srow * NG + colG + n]);
            *(bf16*)(Wg + (size_t)n * ROWB + ((k * 2) ^ ((n & 7) << 4))) = v;
        }
        const int colC = cgC * 16;
        for (int idx = tid; idx < 16 * KRES; idx += 512) {
            const int n = idx & 15, k = idx >> 4;
            const int srow = STREAM_X ? (IN + k) : k;
            bf16 v = f2bf(ckF[(size_t)srow * NC + colC + n]);
            *(bf16*)(Wc + (size_t)n * ROWB + ((k * 2) ^ ((n & 7) << 4))) = v;
        }
    }
    __syncthreads();

    const bool actG = (wv * FPW) < FG;
    const bool actC = wv < FC;
    const int  swz  = (l16 & 7) << 4;
    unsigned   nbar = 0;

    for (int t = t0; t < t1; ++t) {
        const bf16* xb = Xall + (size_t)(t - xbase) * 256 * IN;
        // ======================= gates =======================
        if (actG) {
            floatx4 acc[FPW] = {};
            int rowA[FPW];
#pragma unroll
            for (int j = 0; j < FPW; ++j)
                rowA[j] = mbG * MRG + (wv * FPW + j) * 16 + l16;

            // x-part of K (stable data: plain cached loads)
#pragma unroll 4
            for (int kb = 0; kb < IN / 32; ++kb) {
                short8 b;
                if constexpr (STREAM_X)
                    b = *(const short8*)(WgxT + (size_t)(cgG * 16 + l16) * IN + kb * 32 + quad * 8);
                else
                    b = *(const short8*)(Wg + (size_t)l16 * ROWB + ((kb * 64 + quad * 16) ^ swz));
#pragma unroll
                for (int j = 0; j < FPW; ++j) {
                    short8 a = *(const short8*)(xb + (size_t)rowA[j] * IN + kb * 32 + quad * 8);
                    acc[j] = __builtin_amdgcn_mfma_f32_16x16x32_bf16(a, b, acc[j], 0, 0, 0);
                }
            }
            // h-part of K (cross-WG state: coherent loads)
#pragma unroll 4
            for (int kb = 0; kb < OUT / 32; ++kb) {
                short8 b = *(const short8*)(Wg + (size_t)l16 * ROWB +
                                            ((KH0 * 2 + kb * 64 + quad * 16) ^ swz));
#pragma unroll
                for (int j = 0; j < FPW; ++j) {
                    short8 a = cload8(hB + (size_t)rowA[j] * OUT + kb * 32 + quad * 8);
                    acc[j] = __builtin_amdgcn_mfma_f32_16x16x32_bf16(a, b, acc[j], 0, 0, 0);
                }
            }
            // epilogue: sigmoid; r-half -> rh = r*h, z-half -> zb
            const int col   = cgG * 16 + l16;
            const float bia = gbF[col];
            const bool isR  = (cgG * 16) < OUT;
#pragma unroll
            for (int j = 0; j < FPW; ++j) {
#pragma unroll
                for (int r = 0; r < 4; ++r) {
                    const int row = mbG * MRG + (wv * FPW + j) * 16 + quad * 4 + r;
                    float v = acc[j][r] + bia;
                    float s = 1.f / (1.f + __expf(-v));
                    if (isR) {
                        size_t idx = (size_t)row * OUT + col;
                        cstore_bf16(rhB + idx, s * cload_f32(hF + idx));
                    } else {
                        cstore_f32(zbF + (size_t)row * OUT + (col - OUT), s);
                    }
                }
            }
        }
        dev_barrier(bar_ctr, (++nbar) * 256u);

        // ===================== candidate =====================
        if (actC) {
            floatx4 acc = {};
            const int rowA = mbC * MRC + wv * 16 + l16;

#pragma unroll 4
            for (int kb = 0; kb < IN / 32; ++kb) {
                short8 b;
                if constexpr (STREAM_X)
                    b = *(const short8*)(WcxT + (size_t)(cgC * 16 + l16) * IN + kb * 32 + quad * 8);
                else
                    b = *(const short8*)(Wc + (size_t)l16 * ROWB + ((kb * 64 + quad * 16) ^ swz));
                short8 a = *(const short8*)(xb + (size_t)rowA * IN + kb * 32 + quad * 8);
                acc = __builtin_amdgcn_mfma_f32_16x16x32_bf16(a, b, acc, 0, 0, 0);
            }
#pragma unroll 4
            for (int kb = 0; kb < OUT / 32; ++kb) {
                short8 b = *(const short8*)(Wc + (size_t)l16 * ROWB +
                                            ((KH0 * 2 + kb * 64 + quad * 16) ^ swz));
                short8 a = cload8(rhB + (size_t)rowA * OUT + kb * 32 + quad * 8);
                acc = __builtin_amdgcn_mfma_f32_16x16x32_bf16(a, b, acc, 0, 0, 0);
            }
            const int col   = cgC * 16 + l16;
            const float bia = cbF[col];
#pragma unroll
            for (int r = 0; r < 4; ++r) {
                const int row = mbC * MRC + wv * 16 + quad * 4 + r;
                float v = acc[r] + bia;
                float c = tanhf(v);
                size_t idx = (size_t)row * OUT + col;
                float z = cload_f32(zbF + idx);
                float ho = cload_f32(hF + idx);
                float hn = (t < lens[row]) ? (z * ho + (1.f - z) * c) : ho;
                cstore_f32(hF + idx, hn);
                cstore_bf16(hB + idx, hn);
                if constexpr (WRITE_ALL)
                    Hall[(size_t)(t - t0) * 256 * OUT + idx] = f2bf(hn);
            }
        }
        dev_barrier(bar_ctr, (++nbar) * 256u);
    }
}

// =================================================================
extern "C" void kernel_launch(void* const* d_in, const int* in_sizes, int n_in,
                              void* d_out, int out_size, void* d_ws, size_t ws_size,
                              hipStream_t stream)
{
    (void)in_sizes; (void)n_in; (void)out_size; (void)ws_size;

    const int*   seq  = (const int*)d_in[0];
    const int*   lens = (const int*)d_in[1];
    const float* tab  = (const float*)d_in[2];
    const float* gkF[3] = {(const float*)d_in[3], (const float*)d_in[7], (const float*)d_in[11]};
    const float* gbF[3] = {(const float*)d_in[4], (const float*)d_in[8], (const float*)d_in[12]};
    const float* ckF[3] = {(const float*)d_in[5], (const float*)d_in[9], (const float*)d_in[13]};
    const float* cbF[3] = {(const float*)d_in[6], (const float*)d_in[10], (const float*)d_in[14]};
    const float* dwF = (const float*)d_in[15];
    const float* dbF = (const float*)d_in[16];
    float* y = (float*)d_out;

    const int outs[3] = {512, 1024, 2048};

    char* w = (char*)d_ws;
    auto alloc = [&](size_t bytes) -> void* {
        void* p = (void*)w;
        w += (bytes + 255) & ~(size_t)255;
        return p;
    };

    // workspace (~56 MB)
    bf16* WgxT    = (bf16*)alloc((size_t)4096 * 1024 * sizeof(bf16));
    bf16* WcxT    = (bf16*)alloc((size_t)2048 * 1024 * sizeof(bf16));
    bf16* emb_all = (bf16*)alloc((size_t)T_ * B_ * 32 * sizeof(bf16));
    bf16* H0c     = (bf16*)alloc((size_t)CH * B_ * 512 * sizeof(bf16));
    bf16* H1c     = (bf16*)alloc((size_t)CH * B_ * 1024 * sizeof(bf16));
    float* hf[3]; bf16* hb[3]; bf16* rh[3]; float* zb[3];
    for (int l = 0; l < 3; ++l) {
        hf[l] = (float*)alloc((size_t)B_ * outs[l] * sizeof(float));
        hb[l] = (bf16*)alloc((size_t)B_ * outs[l] * sizeof(bf16));
        rh[l] = (bf16*)alloc((size_t)B_ * outs[l] * sizeof(bf16));
        zb[l] = (float*)alloc((size_t)B_ * outs[l] * sizeof(float));
    }
    bf16* dw = (bf16*)alloc((size_t)3584 * 512 * sizeof(bf16));
    bf16* db = (bf16*)alloc((size_t)512 * sizeof(bf16));
    bf16* cc = (bf16*)alloc((size_t)B_ * 3584 * sizeof(bf16));
    unsigned* bar_ctrs = (unsigned*)alloc(12 * 256);   // one 256B slot per dispatch

    auto kL0 = gru_layer_k<32,   512,  false, true>;
    auto kL1 = gru_layer_k<512,  1024, false, true>;
    auto kL2 = gru_layer_k<1024, 2048, true,  false>;
    const unsigned lds0 = (unsigned)(2 * 16 * row_bytes(32 + 512));
    const unsigned lds1 = (unsigned)(2 * 16 * row_bytes(512 + 1024));
    const unsigned lds2 = (unsigned)(2 * 16 * row_bytes(2048));

    hipFuncSetAttribute((const void*)kL0, hipFuncAttributeMaxDynamicSharedMemorySize, (int)lds0);
    hipFuncSetAttribute((const void*)kL1, hipFuncAttributeMaxDynamicSharedMemorySize, (int)lds1);
    hipFuncSetAttribute((const void*)kL2, hipFuncAttributeMaxDynamicSharedMemorySize, (int)lds2);

    // ---- prep ----
    {
        int n8 = 3584 * 512 / 8;
        cvt_k<<<(n8 + 255) / 256, 256, 0, stream>>>(dwF, dw, n8);
        cvt_k<<<1, 256, 0, stream>>>(dbF, db, 512 / 8);
    }
    embed_k<<<T_ * B_ * 4 / 256, 256, 0, stream>>>(seq, tab, emb_all);
    transpose_bf16_k<<<dim3(1024 / 32, 4096 / 32), 256, 0, stream>>>(gkF[2], 4096, WgxT, 1024, 4096);
    transpose_bf16_k<<<dim3(1024 / 32, 2048 / 32), 256, 0, stream>>>(ckF[2], 2048, WcxT, 1024, 2048);

    for (int l = 0; l < 3; ++l) {
        hipMemsetAsync(hf[l], 0, (size_t)B_ * outs[l] * sizeof(float), stream);
        hipMemsetAsync(hb[l], 0, (size_t)B_ * outs[l] * sizeof(bf16), stream);
    }
    hipMemsetAsync(bar_ctrs, 0, 12 * 256, stream);

    // ---- recurrent layers: 32-step chunks, L0 -> L1 -> L2 per chunk ----
    for (int c = 0; c < T_ / CH; ++c) {
        int t0 = c * CH, t1 = t0 + CH;
        {
            const bf16* xall = emb_all;
            const float *g = gkF[0], *gb_ = gbF[0], *cw = ckF[0], *cb_ = cbF[0];
            const bf16 *wgx = nullptr, *wcx = nullptr;
            float* hf_ = hf[0]; bf16* hb_ = hb[0]; bf16* rh_ = rh[0]; float* zb_ = zb[0];
            bf16* hall = H0c; unsigned* bc = bar_ctrs + (c * 3 + 0) * 64; int xb = 0;
            void* args[] = {&xall, &g, &gb_, &cw, &cb_, &wgx, &wcx, (void*)&lens,
                            &hf_, &hb_, &rh_, &zb_, &hall, &bc, &t0, &t1, &xb};
            hipLaunchCooperativeKernel((const void*)kL0, dim3(256), dim3(512), args, lds0, stream);
        }
        {
            const bf16* xall = H0c;
            const float *g = gkF[1], *gb_ = gbF[1], *cw = ckF[1], *cb_ = cbF[1];
            const bf16 *wgx = nullptr, *wcx = nullptr;
            float* hf_ = hf[1]; bf16* hb_ = hb[1]; bf16* rh_ = rh[1]; float* zb_ = zb[1];
            bf16* hall = H1c; unsigned* bc = bar_ctrs + (c * 3 + 1) * 64; int xb = t0;
            void* args[] = {&xall, &g, &gb_, &cw, &cb_, &wgx, &wcx, (void*)&lens,
                            &hf_, &hb_, &rh_, &zb_, &hall, &bc, &t0, &t1, &xb};
            hipLaunchCooperativeKernel((const void*)kL1, dim3(256), dim3(512), args, lds1, stream);
        }
        {
            const bf16* xall = H1c;
            const float *g = gkF[2], *gb_ = gbF[2], *cw = ckF[2], *cb_ = cbF[2];
            const bf16 *wgx = WgxT, *wcx = WcxT;
            float* hf_ = hf[2]; bf16* hb_ = hb[2]; bf16* rh_ = rh[2]; float* zb_ = zb[2];
            bf16* hall = nullptr; unsigned* bc = bar_ctrs + (c * 3 + 2) * 64; int xb = t0;
            void* args[] = {&xall, &g, &gb_, &cw, &cb_, &wgx, &wcx, (void*)&lens,
                            &hf_, &hb_, &rh_, &zb_, &hall, &bc, &t0, &t1, &xb};
            hipLaunchCooperativeKernel((const void*)kL2, dim3(256), dim3(512), args, lds2, stream);
        }
    }

    // ---- head ----
    concat_k<<<B_ * 3584 / 8 / 256, 256, 0, stream>>>(hf[0], hf[1], hf[2], cc);
    dense_k<<<dim3(512 / 64, 256 / 64), 256, 0, stream>>>(cc, dw, db, y);
}

// Round 5
// 24262.807 us; speedup vs baseline: 1.6372x; 1.1025x over previous
//
#include <hip/hip_runtime.h>
#include <hip/hip_bf16.h>

using bf16 = __hip_bfloat16;

typedef __attribute__((ext_vector_type(8))) short short8;
typedef __attribute__((ext_vector_type(4))) float floatx4;

static constexpr int B_ = 256;   // batch
static constexpr int T_ = 128;   // time steps
static constexpr int CH = 32;    // time-chunk (history buffers sized to this)

__device__ __forceinline__ float bf2f(bf16 v) { return __bfloat162float(v); }
__device__ __forceinline__ bf16  f2bf(float v) { return __float2bfloat16(v); }

// round row bytes up to a multiple of 128 so the XOR swizzle (flips byte
// bits 4..6, i.e. permutes 16B blocks within a 128B stripe) stays in-row.
constexpr size_t row_bytes(int kres) { return ((size_t)kres * 2 + 127) & ~(size_t)127; }

// ---------------- device-coherent access helpers (cross-XCD, no L2 flush) ----
__device__ __forceinline__ void cstore_f32(float* p, float v) {
    asm volatile("global_store_dword %0, %1, off sc0 sc1" :: "v"(p), "v"(v) : "memory");
}
__device__ __forceinline__ void cstore_bf16(bf16* p, float v) {
    bf16 b = f2bf(v);
    unsigned u = *(unsigned short*)&b;
    asm volatile("global_store_short %0, %1, off sc0 sc1" :: "v"(p), "v"(u) : "memory");
}
__device__ __forceinline__ float cload_f32(const float* p) {
    unsigned v = __hip_atomic_load((const unsigned*)p, __ATOMIC_RELAXED, __HIP_MEMORY_SCOPE_AGENT);
    return __uint_as_float(v);
}
__device__ __forceinline__ short8 cload8(const bf16* p) {
    union { unsigned long long q[2]; short8 v; } u;
    const unsigned long long* pp = (const unsigned long long*)p;
    u.q[0] = __hip_atomic_load(pp,     __ATOMIC_RELAXED, __HIP_MEMORY_SCOPE_AGENT);
    u.q[1] = __hip_atomic_load(pp + 1, __ATOMIC_RELAXED, __HIP_MEMORY_SCOPE_AGENT);
    return u.v;
}

// Hierarchical device-wide barrier (no L2 flush, no same-line RMW/poll conflict):
// 8 group counter lines (32 arrivals each) -> 1 root line (8 arrivals) ->
// flag line written once per epoch; leaders poll only the read-mostly flag.
// bs layout (u32 index): group i ctr at [i*16], root at [128], flag at [144].
__device__ __forceinline__ void dev_barrier2(unsigned* bs, unsigned epoch) {
    asm volatile("s_waitcnt vmcnt(0)" ::: "memory");
    __syncthreads();
    if (threadIdx.x == 0) {
        unsigned g = blockIdx.x & 7;
        unsigned old = __hip_atomic_fetch_add(bs + g * 16, 1u,
                          __ATOMIC_RELAXED, __HIP_MEMORY_SCOPE_AGENT);
        if (old == epoch * 32u - 1u) {
            unsigned r = __hip_atomic_fetch_add(bs + 128, 1u,
                            __ATOMIC_RELAXED, __HIP_MEMORY_SCOPE_AGENT);
            if (r == epoch * 8u - 1u)
                __hip_atomic_store(bs + 144, epoch,
                                   __ATOMIC_RELAXED, __HIP_MEMORY_SCOPE_AGENT);
        }
        while (__hip_atomic_load(bs + 144, __ATOMIC_RELAXED,
                                 __HIP_MEMORY_SCOPE_AGENT) < epoch)
            __builtin_amdgcn_s_sleep(4);
        asm volatile("" ::: "memory");
    }
    __syncthreads();
}

// ---------------------------------------------------------------- fp32->bf16
__global__ __launch_bounds__(256) void cvt_k(const float* __restrict__ src,
                                             bf16* __restrict__ dst, int n8)
{
    int i = blockIdx.x * 256 + threadIdx.x;
    if (i >= n8) return;
    const float* s = src + (size_t)i * 8;
    float4 a = *(const float4*)s;
    float4 b = *(const float4*)(s + 4);
    bf16 t[8] = {f2bf(a.x), f2bf(a.y), f2bf(a.z), f2bf(a.w),
                 f2bf(b.x), f2bf(b.y), f2bf(b.z), f2bf(b.w)};
    *(uint4*)(dst + (size_t)i * 8) = *(uint4*)t;
}

// ------------------------------------------------------------------ embedding
__global__ __launch_bounds__(256) void embed_k(const int* __restrict__ seq,
                                               const float* __restrict__ tab,
                                               bf16* __restrict__ emb_all)
{
    int c = blockIdx.x * 256 + threadIdx.x;
    int t = c >> 10;
    int r = c & 1023;
    int b = r >> 2, i = r & 3;
    int tok = seq[b * T_ + t];
    const float* s = tab + (size_t)tok * 32 + i * 8;
    bf16 tmp[8];
#pragma unroll
    for (int j = 0; j < 8; ++j) tmp[j] = f2bf(s[j]);
    *(uint4*)(emb_all + ((size_t)t * B_ + b) * 32 + i * 8) = *(uint4*)tmp;
}

// ----------------------------------------------------- fp32 -> bf16 transpose
__global__ __launch_bounds__(256) void transpose_bf16_k(
    const float* __restrict__ in, int ldin, bf16* __restrict__ out, int K, int N)
{
    __shared__ float tile[32][33];
    const int bk = blockIdx.x * 32, bn = blockIdx.y * 32;
    const int tx = threadIdx.x & 31, ty = threadIdx.x >> 5;
#pragma unroll
    for (int i = 0; i < 32; i += 8)
        tile[ty + i][tx] = in[(size_t)(bk + ty + i) * ldin + (bn + tx)];
    __syncthreads();
#pragma unroll
    for (int i = 0; i < 32; i += 8)
        out[(size_t)(bn + ty + i) * K + (bk + tx)] = f2bf(tile[tx][ty + i]);
}

// ------------------------------------------------------------------- concat
__global__ __launch_bounds__(256) void concat_k(const float* __restrict__ h0,
                                                const float* __restrict__ h1,
                                                const float* __restrict__ h2,
                                                bf16* __restrict__ cc)
{
    int c = blockIdx.x * 256 + threadIdx.x;
    int b = c / 448;
    int j = (c % 448) * 8;
    const float* src;
    if (j < 512)        src = h0 + (size_t)b * 512 + j;
    else if (j < 1536)  src = h1 + (size_t)b * 1024 + (j - 512);
    else                src = h2 + (size_t)b * 2048 + (j - 1536);
    bf16 tmp[8];
#pragma unroll
    for (int i = 0; i < 8; ++i) tmp[i] = f2bf(src[i]);
    *(uint4*)(cc + (size_t)b * 3584 + j) = *(uint4*)tmp;
}

// --------------------------------------------------------------- final dense
__global__ __launch_bounds__(256) void dense_k(const bf16* __restrict__ A,
                                               const bf16* __restrict__ Bw,
                                               const bf16* __restrict__ bias,
                                               float* __restrict__ yout)
{
    __shared__ __align__(16) bf16 As[64 * 40];
    __shared__ __align__(16) bf16 Bs[64 * 40];

    const int tid  = threadIdx.x;
    const int bm   = blockIdx.y * 64;
    const int bn   = blockIdx.x * 64;
    const int lane = tid & 63;
    const int wave = tid >> 6;
    const int wm   = (wave >> 1) * 32;
    const int wn   = (wave & 1) * 32;
    const int quad = lane >> 4;
    const int l16  = lane & 15;

    floatx4 acc[2][2] = {};

    const int ar = tid >> 2, ak = (tid & 3) * 8;
    const int bk = tid >> 3, bn0 = (tid & 7) * 8;

    for (int k0 = 0; k0 < 3584; k0 += 32) {
        uint4 av = *(const uint4*)(A + (size_t)(bm + ar) * 3584 + k0 + ak);
        *(uint4*)&As[ar * 40 + ak] = av;
        uint4 bv = *(const uint4*)(Bw + (size_t)(k0 + bk) * 512 + bn + bn0);
        bf16 tmp[8];
        *(uint4*)tmp = bv;
#pragma unroll
        for (int i = 0; i < 8; ++i) Bs[(bn0 + i) * 40 + bk] = tmp[i];
        __syncthreads();

        short8 af0 = *(const short8*)&As[(wm + l16) * 40 + quad * 8];
        short8 af1 = *(const short8*)&As[(wm + 16 + l16) * 40 + quad * 8];
        short8 bw0 = *(const short8*)&Bs[(wn + l16) * 40 + quad * 8];
        short8 bw1 = *(const short8*)&Bs[(wn + 16 + l16) * 40 + quad * 8];

        acc[0][0] = __builtin_amdgcn_mfma_f32_16x16x32_bf16(af0, bw0, acc[0][0], 0, 0, 0);
        acc[0][1] = __builtin_amdgcn_mfma_f32_16x16x32_bf16(af0, bw1, acc[0][1], 0, 0, 0);
        acc[1][0] = __builtin_amdgcn_mfma_f32_16x16x32_bf16(af1, bw0, acc[1][0], 0, 0, 0);
        acc[1][1] = __builtin_amdgcn_mfma_f32_16x16x32_bf16(af1, bw1, acc[1][1], 0, 0, 0);
        __syncthreads();
    }

#pragma unroll
    for (int tm = 0; tm < 2; ++tm)
#pragma unroll
        for (int tn = 0; tn < 2; ++tn)
#pragma unroll
            for (int r = 0; r < 4; ++r) {
                const int row = bm + wm + tm * 16 + quad * 4 + r;
                const int col = bn + wn + tn * 16 + l16;
                float v = acc[tm][tn][r] + bf2f(bias[col]);
                yout[(size_t)row * 512 + col] = tanhf(v);
            }
}

// =================================================================
// Persistent GRU layer over a time chunk [t0, t1).
// Phase-balanced schedule: x-part matmuls (no dependency on the
// just-synced state) are hoisted into the opposite phase so each
// barrier-to-barrier region has independent work hiding latency:
//   phase G: gates-h (+epi: rh,z)  | cand-x(t)     -> barrier
//   phase C: cand-h  (+epi: h)     | gates-x(t+1)  -> barrier
// Accumulation order per accumulator is unchanged (x then h) ->
// bit-identical to the round-3/4 passing kernels.
// =================================================================
template <int IN, int OUT, bool STREAM_X, bool WRITE_ALL>
__global__ __launch_bounds__(512) void gru_layer_k(
    const bf16* __restrict__ Xall,
    const float* __restrict__ gkF,
    const float* __restrict__ gbF,
    const float* __restrict__ ckF,
    const float* __restrict__ cbF,
    const bf16* __restrict__ WgxT,
    const bf16* __restrict__ WcxT,
    const int* __restrict__ lens,
    float* __restrict__ hF,
    bf16* __restrict__ hB,
    bf16* __restrict__ rhB,
    float* __restrict__ zbF,
    bf16* __restrict__ Hall,
    unsigned* __restrict__ bar,
    int t0, int t1, int xbase)
{
    constexpr int NG = 2 * OUT, NC = OUT;
    constexpr int KRES = STREAM_X ? OUT : (IN + OUT);
    constexpr int NWG = NG / 16, MSG = 256 / NWG, MRG = 256 / MSG, FG = MRG / 16;
    constexpr int NWC = NC / 16, MSC = 256 / NWC, MRC = 256 / MSC, FC = MRC / 16;
    constexpr int FPW = (FG >= 8) ? (FG / 8) : 1;
    constexpr size_t ROWB = row_bytes(KRES);
    constexpr int KH0 = STREAM_X ? 0 : IN;

    extern __shared__ char lds[];
    char* Wg = lds;
    char* Wc = lds + (size_t)16 * ROWB;

    const int tid  = threadIdx.x;
    const int wgid = blockIdx.x;
    const int wv   = tid >> 6;
    const int lane = tid & 63;
    const int l16  = lane & 15;
    const int quad = lane >> 4;

    const int cgG = wgid / MSG, mbG = wgid % MSG;
    const int cgC = wgid / MSC, mbC = wgid % MSC;

    // ---- load resident weight slices into LDS (swizzled [16][KRES]) ----
    {
        const int colG = cgG * 16;
        for (int idx = tid; idx < 16 * KRES; idx += 512) {
            const int n = idx & 15, k = idx >> 4;
            const int srow = STREAM_X ? (IN + k) : k;
            bf16 v = f2bf(gkF[(size_t)srow * NG + colG + n]);
            *(bf16*)(Wg + (size_t)n * ROWB + ((k * 2) ^ ((n & 7) << 4))) = v;
        }
        const int colC = cgC * 16;
        for (int idx = tid; idx < 16 * KRES; idx += 512) {
            const int n = idx & 15, k = idx >> 4;
            const int srow = STREAM_X ? (IN + k) : k;
            bf16 v = f2bf(ckF[(size_t)srow * NC + colC + n]);
            *(bf16*)(Wc + (size_t)n * ROWB + ((k * 2) ^ ((n & 7) << 4))) = v;
        }
    }
    __syncthreads();

    const bool actG = (wv * FPW) < FG;
    const bool actC = wv < FC;
    const int  swz  = (l16 & 7) << 4;

    floatx4 accG[FPW];
    floatx4 accC;

    int rowAG[FPW];
#pragma unroll
    for (int j = 0; j < FPW; ++j)
        rowAG[j] = mbG * MRG + (wv * FPW + j) * 16 + l16;
    const int rowAC = mbC * MRC + wv * 16 + l16;

    auto gates_x = [&](int t) {
        if (!actG) return;
#pragma unroll
        for (int j = 0; j < FPW; ++j) accG[j] = (floatx4){0.f, 0.f, 0.f, 0.f};
        const bf16* xb = Xall + (size_t)(t - xbase) * 256 * IN;
#pragma unroll 4
        for (int kb = 0; kb < IN / 32; ++kb) {
            short8 b;
            if constexpr (STREAM_X)
                b = *(const short8*)(WgxT + (size_t)(cgG * 16 + l16) * IN + kb * 32 + quad * 8);
            else
                b = *(const short8*)(Wg + (size_t)l16 * ROWB + ((kb * 64 + quad * 16) ^ swz));
#pragma unroll
            for (int j = 0; j < FPW; ++j) {
                short8 a = *(const short8*)(xb + (size_t)rowAG[j] * IN + kb * 32 + quad * 8);
                accG[j] = __builtin_amdgcn_mfma_f32_16x16x32_bf16(a, b, accG[j], 0, 0, 0);
            }
        }
    };

    auto cand_x = [&](int t) {
        if (!actC) return;
        accC = (floatx4){0.f, 0.f, 0.f, 0.f};
        const bf16* xb = Xall + (size_t)(t - xbase) * 256 * IN;
#pragma unroll 4
        for (int kb = 0; kb < IN / 32; ++kb) {
            short8 b;
            if constexpr (STREAM_X)
                b = *(const short8*)(WcxT + (size_t)(cgC * 16 + l16) * IN + kb * 32 + quad * 8);
            else
                b = *(const short8*)(Wc + (size_t)l16 * ROWB + ((kb * 64 + quad * 16) ^ swz));
            short8 a = *(const short8*)(xb + (size_t)rowAC * IN + kb * 32 + quad * 8);
            accC = __builtin_amdgcn_mfma_f32_16x16x32_bf16(a, b, accC, 0, 0, 0);
        }
    };

    unsigned epoch = 0;
    gates_x(t0);

    for (int t = t0; t < t1; ++t) {
        // =============== phase G: gates-h + epilogue, then cand-x(t) ========
        if (actG) {
#pragma unroll 4
            for (int kb = 0; kb < OUT / 32; ++kb) {
                short8 b = *(const short8*)(Wg + (size_t)l16 * ROWB +
                                            ((KH0 * 2 + kb * 64 + quad * 16) ^ swz));
#pragma unroll
                for (int j = 0; j < FPW; ++j) {
                    short8 a = cload8(hB + (size_t)rowAG[j] * OUT + kb * 32 + quad * 8);
                    accG[j] = __builtin_amdgcn_mfma_f32_16x16x32_bf16(a, b, accG[j], 0, 0, 0);
                }
            }
            const int col   = cgG * 16 + l16;
            const float bia = gbF[col];
            const bool isR  = (cgG * 16) < OUT;
#pragma unroll
            for (int j = 0; j < FPW; ++j) {
#pragma unroll
                for (int r = 0; r < 4; ++r) {
                    const int row = mbG * MRG + (wv * FPW + j) * 16 + quad * 4 + r;
                    float v = accG[j][r] + bia;
                    float s = 1.f / (1.f + __expf(-v));
                    if (isR) {
                        size_t idx = (size_t)row * OUT + col;
                        cstore_bf16(rhB + idx, s * cload_f32(hF + idx));
                    } else {
                        cstore_f32(zbF + (size_t)row * OUT + (col - OUT), s);
                    }
                }
            }
        }
        cand_x(t);
        dev_barrier2(bar, ++epoch);

        // =============== phase C: cand-h + epilogue, then gates-x(t+1) ======
        if (actC) {
#pragma unroll 4
            for (int kb = 0; kb < OUT / 32; ++kb) {
                short8 b = *(const short8*)(Wc + (size_t)l16 * ROWB +
                                            ((KH0 * 2 + kb * 64 + quad * 16) ^ swz));
                short8 a = cload8(rhB + (size_t)rowAC * OUT + kb * 32 + quad * 8);
                accC = __builtin_amdgcn_mfma_f32_16x16x32_bf16(a, b, accC, 0, 0, 0);
            }
            const int col   = cgC * 16 + l16;
            const float bia = cbF[col];
#pragma unroll
            for (int r = 0; r < 4; ++r) {
                const int row = mbC * MRC + wv * 16 + quad * 4 + r;
                float v = accC[r] + bia;
                float c = tanhf(v);
                size_t idx = (size_t)row * OUT + col;
                float z = cload_f32(zbF + idx);
                float ho = cload_f32(hF + idx);
                float hn = (t < lens[row]) ? (z * ho + (1.f - z) * c) : ho;
                cstore_f32(hF + idx, hn);
                cstore_bf16(hB + idx, hn);
                if constexpr (WRITE_ALL)
                    Hall[(size_t)(t - t0) * 256 * OUT + idx] = f2bf(hn);
            }
        }
        if (t + 1 < t1) gates_x(t + 1);
        dev_barrier2(bar, ++epoch);
    }
}

// =================================================================
extern "C" void kernel_launch(void* const* d_in, const int* in_sizes, int n_in,
                              void* d_out, int out_size, void* d_ws, size_t ws_size,
                              hipStream_t stream)
{
    (void)in_sizes; (void)n_in; (void)out_size; (void)ws_size;

    const int*   seq  = (const int*)d_in[0];
    const int*   lens = (const int*)d_in[1];
    const float* tab  = (const float*)d_in[2];
    const float* gkF[3] = {(const float*)d_in[3], (const float*)d_in[7], (const float*)d_in[11]};
    const float* gbF[3] = {(const float*)d_in[4], (const float*)d_in[8], (const float*)d_in[12]};
    const float* ckF[3] = {(const float*)d_in[5], (const float*)d_in[9], (const float*)d_in[13]};
    const float* cbF[3] = {(const float*)d_in[6], (const float*)d_in[10], (const float*)d_in[14]};
    const float* dwF = (const float*)d_in[15];
    const float* dbF = (const float*)d_in[16];
    float* y = (float*)d_out;

    const int outs[3] = {512, 1024, 2048};

    char* w = (char*)d_ws;
    auto alloc = [&](size_t bytes) -> void* {
        void* p = (void*)w;
        w += (bytes + 255) & ~(size_t)255;
        return p;
    };

    // workspace (~56 MB)
    bf16* WgxT    = (bf16*)alloc((size_t)4096 * 1024 * sizeof(bf16));
    bf16* WcxT    = (bf16*)alloc((size_t)2048 * 1024 * sizeof(bf16));
    bf16* emb_all = (bf16*)alloc((size_t)T_ * B_ * 32 * sizeof(bf16));
    bf16* H0c     = (bf16*)alloc((size_t)CH * B_ * 512 * sizeof(bf16));
    bf16* H1c     = (bf16*)alloc((size_t)CH * B_ * 1024 * sizeof(bf16));
    float* hf[3]; bf16* hb[3]; bf16* rh[3]; float* zb[3];
    for (int l = 0; l < 3; ++l) {
        hf[l] = (float*)alloc((size_t)B_ * outs[l] * sizeof(float));
        hb[l] = (bf16*)alloc((size_t)B_ * outs[l] * sizeof(bf16));
        rh[l] = (bf16*)alloc((size_t)B_ * outs[l] * sizeof(bf16));
        zb[l] = (float*)alloc((size_t)B_ * outs[l] * sizeof(float));
    }
    bf16* dw = (bf16*)alloc((size_t)3584 * 512 * sizeof(bf16));
    bf16* db = (bf16*)alloc((size_t)512 * sizeof(bf16));
    bf16* cc = (bf16*)alloc((size_t)B_ * 3584 * sizeof(bf16));
    unsigned* bar_area = (unsigned*)alloc(12 * 1024);   // 12 slots x 1KB

    auto kL0 = gru_layer_k<32,   512,  false, true>;
    auto kL1 = gru_layer_k<512,  1024, false, true>;
    auto kL2 = gru_layer_k<1024, 2048, true,  false>;
    const unsigned lds0 = (unsigned)(2 * 16 * row_bytes(32 + 512));
    const unsigned lds1 = (unsigned)(2 * 16 * row_bytes(512 + 1024));
    const unsigned lds2 = (unsigned)(2 * 16 * row_bytes(2048));

    hipFuncSetAttribute((const void*)kL0, hipFuncAttributeMaxDynamicSharedMemorySize, (int)lds0);
    hipFuncSetAttribute((const void*)kL1, hipFuncAttributeMaxDynamicSharedMemorySize, (int)lds1);
    hipFuncSetAttribute((const void*)kL2, hipFuncAttributeMaxDynamicSharedMemorySize, (int)lds2);

    // ---- prep ----
    {
        int n8 = 3584 * 512 / 8;
        cvt_k<<<(n8 + 255) / 256, 256, 0, stream>>>(dwF, dw, n8);
        cvt_k<<<1, 256, 0, stream>>>(dbF, db, 512 / 8);
    }
    embed_k<<<T_ * B_ * 4 / 256, 256, 0, stream>>>(seq, tab, emb_all);
    transpose_bf16_k<<<dim3(1024 / 32, 4096 / 32), 256, 0, stream>>>(gkF[2], 4096, WgxT, 1024, 4096);
    transpose_bf16_k<<<dim3(1024 / 32, 2048 / 32), 256, 0, stream>>>(ckF[2], 2048, WcxT, 1024, 2048);

    for (int l = 0; l < 3; ++l) {
        hipMemsetAsync(hf[l], 0, (size_t)B_ * outs[l] * sizeof(float), stream);
        hipMemsetAsync(hb[l], 0, (size_t)B_ * outs[l] * sizeof(bf16), stream);
    }
    hipMemsetAsync(bar_area, 0, 12 * 1024, stream);

    // ---- recurrent layers: 32-step chunks, L0 -> L1 -> L2 per chunk ----
    for (int c = 0; c < T_ / CH; ++c) {
        int t0 = c * CH, t1 = t0 + CH;
        {
            const bf16* xall = emb_all;
            const float *g = gkF[0], *gb_ = gbF[0], *cw = ckF[0], *cb_ = cbF[0];
            const bf16 *wgx = nullptr, *wcx = nullptr;
            float* hf_ = hf[0]; bf16* hb_ = hb[0]; bf16* rh_ = rh[0]; float* zb_ = zb[0];
            bf16* hall = H0c; unsigned* bc = bar_area + (c * 3 + 0) * 256; int xb = 0;
            void* args[] = {&xall, &g, &gb_, &cw, &cb_, &wgx, &wcx, (void*)&lens,
                            &hf_, &hb_, &rh_, &zb_, &hall, &bc, &t0, &t1, &xb};
            hipLaunchCooperativeKernel((const void*)kL0, dim3(256), dim3(512), args, lds0, stream);
        }
        {
            const bf16* xall = H0c;
            const float *g = gkF[1], *gb_ = gbF[1], *cw = ckF[1], *cb_ = cbF[1];
            const bf16 *wgx = nullptr, *wcx = nullptr;
            float* hf_ = hf[1]; bf16* hb_ = hb[1]; bf16* rh_ = rh[1]; float* zb_ = zb[1];
            bf16* hall = H1c; unsigned* bc = bar_area + (c * 3 + 1) * 256; int xb = t0;
            void* args[] = {&xall, &g, &gb_, &cw, &cb_, &wgx, &wcx, (void*)&lens,
                            &hf_, &hb_, &rh_, &zb_, &hall, &bc, &t0, &t1, &xb};
            hipLaunchCooperativeKernel((const void*)kL1, dim3(256), dim3(512), args, lds1, stream);
        }
        {
            const bf16* xall = H1c;
            const float *g = gkF[2], *gb_ = gbF[2], *cw = ckF[2], *cb_ = cbF[2];
            const bf16 *wgx = WgxT, *wcx = WcxT;
            float* hf_ = hf[2]; bf16* hb_ = hb[2]; bf16* rh_ = rh[2]; float* zb_ = zb[2];
            bf16* hall = nullptr; unsigned* bc = bar_area + (c * 3 + 2) * 256; int xb = t0;
            void* args[] = {&xall, &g, &gb_, &cw, &cb_, &wgx, &wcx, (void*)&lens,
                            &hf_, &hb_, &rh_, &zb_, &hall, &bc, &t0, &t1, &xb};
            hipLaunchCooperativeKernel((const void*)kL2, dim3(256), dim3(512), args, lds2, stream);
        }
    }

    // ---- head ----
    concat_k<<<B_ * 3584 / 8 / 256, 256, 0, stream>>>(hf[0], hf[1], hf[2], cc);
    dense_k<<<dim3(512 / 64, 256 / 64), 256, 0, stream>>>(cc, dw, db, y);
}

// Round 6
// 23639.754 us; speedup vs baseline: 1.6803x; 1.0264x over previous
//
#include <hip/hip_runtime.h>
#include <hip/hip_bf16.h>

using bf16 = __hip_bfloat16;

typedef __attribute__((ext_vector_type(8))) short short8;
typedef __attribute__((ext_vector_type(4))) float floatx4;

static constexpr int B_ = 256;   // batch
static constexpr int T_ = 128;   // time steps
static constexpr int CH = 32;    // time-chunk (history buffers sized to this)

__device__ __forceinline__ float bf2f(bf16 v) { return __bfloat162float(v); }
__device__ __forceinline__ bf16  f2bf(float v) { return __float2bfloat16(v); }

// round row bytes up to a multiple of 128 so the XOR swizzle (flips byte
// bits 4..6, i.e. permutes 16B blocks within a 128B stripe) stays in-row.
constexpr size_t row_bytes(int kres) { return ((size_t)kres * 2 + 127) & ~(size_t)127; }

// ---------------- device-coherent access helpers (cross-XCD, no L2 flush) ----
__device__ __forceinline__ void cstore_f32(float* p, float v) {
    asm volatile("global_store_dword %0, %1, off sc0 sc1" :: "v"(p), "v"(v) : "memory");
}
__device__ __forceinline__ void cstore_bf16(bf16* p, float v) {
    bf16 b = f2bf(v);
    unsigned u = *(unsigned short*)&b;
    asm volatile("global_store_short %0, %1, off sc0 sc1" :: "v"(p), "v"(u) : "memory");
}
__device__ __forceinline__ float cload_f32(const float* p) {
    unsigned v = __hip_atomic_load((const unsigned*)p, __ATOMIC_RELAXED, __HIP_MEMORY_SCOPE_AGENT);
    return __uint_as_float(v);
}
__device__ __forceinline__ short8 cload8(const bf16* p) {
    union { unsigned long long q[2]; short8 v; } u;
    const unsigned long long* pp = (const unsigned long long*)p;
    u.q[0] = __hip_atomic_load(pp,     __ATOMIC_RELAXED, __HIP_MEMORY_SCOPE_AGENT);
    u.q[1] = __hip_atomic_load(pp + 1, __ATOMIC_RELAXED, __HIP_MEMORY_SCOPE_AGENT);
    return u.v;
}

// Hierarchical device-wide barrier (no L2 flush, no same-line RMW/poll conflict):
// 8 group counter lines (32 arrivals each) -> 1 root line (8 arrivals) ->
// flag line written once per epoch; leaders poll only the read-mostly flag.
__device__ __forceinline__ void dev_barrier2(unsigned* bs, unsigned epoch) {
    asm volatile("s_waitcnt vmcnt(0)" ::: "memory");
    __syncthreads();
    if (threadIdx.x == 0) {
        unsigned g = blockIdx.x & 7;
        unsigned old = __hip_atomic_fetch_add(bs + g * 16, 1u,
                          __ATOMIC_RELAXED, __HIP_MEMORY_SCOPE_AGENT);
        if (old == epoch * 32u - 1u) {
            unsigned r = __hip_atomic_fetch_add(bs + 128, 1u,
                            __ATOMIC_RELAXED, __HIP_MEMORY_SCOPE_AGENT);
            if (r == epoch * 8u - 1u)
                __hip_atomic_store(bs + 144, epoch,
                                   __ATOMIC_RELAXED, __HIP_MEMORY_SCOPE_AGENT);
        }
        while (__hip_atomic_load(bs + 144, __ATOMIC_RELAXED,
                                 __HIP_MEMORY_SCOPE_AGENT) < epoch)
            __builtin_amdgcn_s_sleep(4);
        asm volatile("" ::: "memory");
    }
    __syncthreads();
}

// ---------------------------------------------------------------- fp32->bf16
__global__ __launch_bounds__(256) void cvt_k(const float* __restrict__ src,
                                             bf16* __restrict__ dst, int n8)
{
    int i = blockIdx.x * 256 + threadIdx.x;
    if (i >= n8) return;
    const float* s = src + (size_t)i * 8;
    float4 a = *(const float4*)s;
    float4 b = *(const float4*)(s + 4);
    bf16 t[8] = {f2bf(a.x), f2bf(a.y), f2bf(a.z), f2bf(a.w),
                 f2bf(b.x), f2bf(b.y), f2bf(b.z), f2bf(b.w)};
    *(uint4*)(dst + (size_t)i * 8) = *(uint4*)t;
}

// ------------------------------------------------------------------ embedding
__global__ __launch_bounds__(256) void embed_k(const int* __restrict__ seq,
                                               const float* __restrict__ tab,
                                               bf16* __restrict__ emb_all)
{
    int c = blockIdx.x * 256 + threadIdx.x;
    int t = c >> 10;
    int r = c & 1023;
    int b = r >> 2, i = r & 3;
    int tok = seq[b * T_ + t];
    const float* s = tab + (size_t)tok * 32 + i * 8;
    bf16 tmp[8];
#pragma unroll
    for (int j = 0; j < 8; ++j) tmp[j] = f2bf(s[j]);
    *(uint4*)(emb_all + ((size_t)t * B_ + b) * 32 + i * 8) = *(uint4*)tmp;
}

// ----------------------------------------------------- fp32 -> bf16 transpose
__global__ __launch_bounds__(256) void transpose_bf16_k(
    const float* __restrict__ in, int ldin, bf16* __restrict__ out, int K, int N)
{
    __shared__ float tile[32][33];
    const int bk = blockIdx.x * 32, bn = blockIdx.y * 32;
    const int tx = threadIdx.x & 31, ty = threadIdx.x >> 5;
#pragma unroll
    for (int i = 0; i < 32; i += 8)
        tile[ty + i][tx] = in[(size_t)(bk + ty + i) * ldin + (bn + tx)];
    __syncthreads();
#pragma unroll
    for (int i = 0; i < 32; i += 8)
        out[(size_t)(bn + ty + i) * K + (bk + tx)] = f2bf(tile[tx][ty + i]);
}

// ------------------------------------------------------------------- concat
__global__ __launch_bounds__(256) void concat_k(const float* __restrict__ h0,
                                                const float* __restrict__ h1,
                                                const float* __restrict__ h2,
                                                bf16* __restrict__ cc)
{
    int c = blockIdx.x * 256 + threadIdx.x;
    int b = c / 448;
    int j = (c % 448) * 8;
    const float* src;
    if (j < 512)        src = h0 + (size_t)b * 512 + j;
    else if (j < 1536)  src = h1 + (size_t)b * 1024 + (j - 512);
    else                src = h2 + (size_t)b * 2048 + (j - 1536);
    bf16 tmp[8];
#pragma unroll
    for (int i = 0; i < 8; ++i) tmp[i] = f2bf(src[i]);
    *(uint4*)(cc + (size_t)b * 3584 + j) = *(uint4*)tmp;
}

// --------------------------------------------------------------- final dense
__global__ __launch_bounds__(256) void dense_k(const bf16* __restrict__ A,
                                               const bf16* __restrict__ Bw,
                                               const bf16* __restrict__ bias,
                                               float* __restrict__ yout)
{
    __shared__ __align__(16) bf16 As[64 * 40];
    __shared__ __align__(16) bf16 Bs[64 * 40];

    const int tid  = threadIdx.x;
    const int bm   = blockIdx.y * 64;
    const int bn   = blockIdx.x * 64;
    const int lane = tid & 63;
    const int wave = tid >> 6;
    const int wm   = (wave >> 1) * 32;
    const int wn   = (wave & 1) * 32;
    const int quad = lane >> 4;
    const int l16  = lane & 15;

    floatx4 acc[2][2] = {};

    const int ar = tid >> 2, ak = (tid & 3) * 8;
    const int bk = tid >> 3, bn0 = (tid & 7) * 8;

    for (int k0 = 0; k0 < 3584; k0 += 32) {
        uint4 av = *(const uint4*)(A + (size_t)(bm + ar) * 3584 + k0 + ak);
        *(uint4*)&As[ar * 40 + ak] = av;
        uint4 bv = *(const uint4*)(Bw + (size_t)(k0 + bk) * 512 + bn + bn0);
        bf16 tmp[8];
        *(uint4*)tmp = bv;
#pragma unroll
        for (int i = 0; i < 8; ++i) Bs[(bn0 + i) * 40 + bk] = tmp[i];
        __syncthreads();

        short8 af0 = *(const short8*)&As[(wm + l16) * 40 + quad * 8];
        short8 af1 = *(const short8*)&As[(wm + 16 + l16) * 40 + quad * 8];
        short8 bw0 = *(const short8*)&Bs[(wn + l16) * 40 + quad * 8];
        short8 bw1 = *(const short8*)&Bs[(wn + 16 + l16) * 40 + quad * 8];

        acc[0][0] = __builtin_amdgcn_mfma_f32_16x16x32_bf16(af0, bw0, acc[0][0], 0, 0, 0);
        acc[0][1] = __builtin_amdgcn_mfma_f32_16x16x32_bf16(af0, bw1, acc[0][1], 0, 0, 0);
        acc[1][0] = __builtin_amdgcn_mfma_f32_16x16x32_bf16(af1, bw0, acc[1][0], 0, 0, 0);
        acc[1][1] = __builtin_amdgcn_mfma_f32_16x16x32_bf16(af1, bw1, acc[1][1], 0, 0, 0);
        __syncthreads();
    }

#pragma unroll
    for (int tm = 0; tm < 2; ++tm)
#pragma unroll
        for (int tn = 0; tn < 2; ++tn)
#pragma unroll
            for (int r = 0; r < 4; ++r) {
                const int row = bm + wm + tm * 16 + quad * 4 + r;
                const int col = bn + wn + tn * 16 + l16;
                float v = acc[tm][tn][r] + bf2f(bias[col]);
                yout[(size_t)row * 512 + col] = tanhf(v);
            }
}

// =================================================================
// Persistent GRU layer over a time chunk [t0, t1).
// Phase-balanced schedule (x-matmuls hoisted into the opposite phase).
// NEW (round 6): the h-part state loads (atomic, cross-XCD coherent)
// are group-staged into registers with a 2-deep double buffer so they
// pipeline (MLP ~16) instead of serializing one LLC latency per 16B
// fragment. All buffer indices are compile-time constants.
// Accumulation order per accumulator is unchanged -> bit-identical.
// =================================================================
template <int IN, int OUT, bool STREAM_X, bool WRITE_ALL>
__global__ __launch_bounds__(512) void gru_layer_k(
    const bf16* __restrict__ Xall,
    const float* __restrict__ gkF,
    const float* __restrict__ gbF,
    const float* __restrict__ ckF,
    const float* __restrict__ cbF,
    const bf16* __restrict__ WgxT,
    const bf16* __restrict__ WcxT,
    const int* __restrict__ lens,
    float* __restrict__ hF,
    bf16* __restrict__ hB,
    bf16* __restrict__ rhB,
    float* __restrict__ zbF,
    bf16* __restrict__ Hall,
    unsigned* __restrict__ bar,
    int t0, int t1, int xbase)
{
    constexpr int NG = 2 * OUT, NC = OUT;
    constexpr int KRES = STREAM_X ? OUT : (IN + OUT);
    constexpr int NWG = NG / 16, MSG = 256 / NWG, MRG = 256 / MSG, FG = MRG / 16;
    constexpr int NWC = NC / 16, MSC = 256 / NWC, MRC = 256 / MSC, FC = MRC / 16;
    constexpr int FPW = (FG >= 8) ? (FG / 8) : 1;
    constexpr size_t ROWB = row_bytes(KRES);
    constexpr int KH0 = STREAM_X ? 0 : IN;
    constexpr int NKB = OUT / 32;          // h-part K-blocks
    constexpr int GK  = 8;                 // K-blocks per load group
    constexpr int NGRP = NKB / GK;
    static_assert(NKB % GK == 0, "group size must divide");

    extern __shared__ char lds[];
    char* Wg = lds;
    char* Wc = lds + (size_t)16 * ROWB;

    const int tid  = threadIdx.x;
    const int wgid = blockIdx.x;
    const int wv   = tid >> 6;
    const int lane = tid & 63;
    const int l16  = lane & 15;
    const int quad = lane >> 4;

    const int cgG = wgid / MSG, mbG = wgid % MSG;
    const int cgC = wgid / MSC, mbC = wgid % MSC;

    // ---- load resident weight slices into LDS (swizzled [16][KRES]) ----
    {
        const int colG = cgG * 16;
        for (int idx = tid; idx < 16 * KRES; idx += 512) {
            const int n = idx & 15, k = idx >> 4;
            const int srow = STREAM_X ? (IN + k) : k;
            bf16 v = f2bf(gkF[(size_t)srow * NG + colG + n]);
            *(bf16*)(Wg + (size_t)n * ROWB + ((k * 2) ^ ((n & 7) << 4))) = v;
        }
        const int colC = cgC * 16;
        for (int idx = tid; idx < 16 * KRES; idx += 512) {
            const int n = idx & 15, k = idx >> 4;
            const int srow = STREAM_X ? (IN + k) : k;
            bf16 v = f2bf(ckF[(size_t)srow * NC + colC + n]);
            *(bf16*)(Wc + (size_t)n * ROWB + ((k * 2) ^ ((n & 7) << 4))) = v;
        }
    }
    __syncthreads();

    const bool actG = (wv * FPW) < FG;
    const bool actC = wv < FC;
    const int  swz  = (l16 & 7) << 4;

    floatx4 accG[FPW];
    floatx4 accC;

    int rowAG[FPW];
#pragma unroll
    for (int j = 0; j < FPW; ++j)
        rowAG[j] = mbG * MRG + (wv * FPW + j) * 16 + l16;
    const int rowAC = mbC * MRC + wv * 16 + l16;

    auto gates_x = [&](int t) {
        if (!actG) return;
#pragma unroll
        for (int j = 0; j < FPW; ++j) accG[j] = (floatx4){0.f, 0.f, 0.f, 0.f};
        const bf16* xb = Xall + (size_t)(t - xbase) * 256 * IN;
#pragma unroll 4
        for (int kb = 0; kb < IN / 32; ++kb) {
            short8 b;
            if constexpr (STREAM_X)
                b = *(const short8*)(WgxT + (size_t)(cgG * 16 + l16) * IN + kb * 32 + quad * 8);
            else
                b = *(const short8*)(Wg + (size_t)l16 * ROWB + ((kb * 64 + quad * 16) ^ swz));
#pragma unroll
            for (int j = 0; j < FPW; ++j) {
                short8 a = *(const short8*)(xb + (size_t)rowAG[j] * IN + kb * 32 + quad * 8);
                accG[j] = __builtin_amdgcn_mfma_f32_16x16x32_bf16(a, b, accG[j], 0, 0, 0);
            }
        }
    };

    auto cand_x = [&](int t) {
        if (!actC) return;
        accC = (floatx4){0.f, 0.f, 0.f, 0.f};
        const bf16* xb = Xall + (size_t)(t - xbase) * 256 * IN;
#pragma unroll 4
        for (int kb = 0; kb < IN / 32; ++kb) {
            short8 b;
            if constexpr (STREAM_X)
                b = *(const short8*)(WcxT + (size_t)(cgC * 16 + l16) * IN + kb * 32 + quad * 8);
            else
                b = *(const short8*)(Wc + (size_t)l16 * ROWB + ((kb * 64 + quad * 16) ^ swz));
            short8 a = *(const short8*)(xb + (size_t)rowAC * IN + kb * 32 + quad * 8);
            accC = __builtin_amdgcn_mfma_f32_16x16x32_bf16(a, b, accC, 0, 0, 0);
        }
    };

    unsigned epoch = 0;
    gates_x(t0);

    for (int t = t0; t < t1; ++t) {
        // =============== phase G: gates-h + epilogue, then cand-x(t) ========
        if (actG) {
            // --- h-part: 2-deep double-buffered grouped atomic loads ---
            short8 ab[2][FPW][GK];
#pragma unroll
            for (int kk = 0; kk < GK; ++kk)
#pragma unroll
                for (int j = 0; j < FPW; ++j)
                    ab[0][j][kk] = cload8(hB + (size_t)rowAG[j] * OUT + kk * 32 + quad * 8);
#pragma unroll
            for (int g = 0; g < NGRP; ++g) {
                constexpr int M2 = 2;
                const int cur = g & 1, nxt = (g & 1) ^ 1; (void)M2;
                if (g + 1 < NGRP) {
#pragma unroll
                    for (int kk = 0; kk < GK; ++kk)
#pragma unroll
                        for (int j = 0; j < FPW; ++j)
                            ab[nxt][j][kk] = cload8(hB + (size_t)rowAG[j] * OUT +
                                                    ((g + 1) * GK + kk) * 32 + quad * 8);
                }
#pragma unroll
                for (int kk = 0; kk < GK; ++kk) {
                    const int kb = g * GK + kk;
                    short8 b = *(const short8*)(Wg + (size_t)l16 * ROWB +
                                                ((KH0 * 2 + kb * 64 + quad * 16) ^ swz));
#pragma unroll
                    for (int j = 0; j < FPW; ++j)
                        accG[j] = __builtin_amdgcn_mfma_f32_16x16x32_bf16(ab[cur][j][kk], b, accG[j], 0, 0, 0);
                }
            }
            // --- epilogue: batch state loads, then compute+store ---
            const int col   = cgG * 16 + l16;
            const float bia = gbF[col];
            const bool isR  = (cgG * 16) < OUT;
            if (isR) {
                float hpre[FPW][4];
#pragma unroll
                for (int j = 0; j < FPW; ++j)
#pragma unroll
                    for (int r = 0; r < 4; ++r) {
                        const int row = mbG * MRG + (wv * FPW + j) * 16 + quad * 4 + r;
                        hpre[j][r] = cload_f32(hF + (size_t)row * OUT + col);
                    }
#pragma unroll
                for (int j = 0; j < FPW; ++j)
#pragma unroll
                    for (int r = 0; r < 4; ++r) {
                        const int row = mbG * MRG + (wv * FPW + j) * 16 + quad * 4 + r;
                        float s = 1.f / (1.f + __expf(-(accG[j][r] + bia)));
                        cstore_bf16(rhB + (size_t)row * OUT + col, s * hpre[j][r]);
                    }
            } else {
#pragma unroll
                for (int j = 0; j < FPW; ++j)
#pragma unroll
                    for (int r = 0; r < 4; ++r) {
                        const int row = mbG * MRG + (wv * FPW + j) * 16 + quad * 4 + r;
                        float s = 1.f / (1.f + __expf(-(accG[j][r] + bia)));
                        cstore_f32(zbF + (size_t)row * OUT + (col - OUT), s);
                    }
            }
        }
        cand_x(t);
        dev_barrier2(bar, ++epoch);

        // =============== phase C: cand-h + epilogue, then gates-x(t+1) ======
        if (actC) {
            short8 cb2[2][GK];
#pragma unroll
            for (int kk = 0; kk < GK; ++kk)
                cb2[0][kk] = cload8(rhB + (size_t)rowAC * OUT + kk * 32 + quad * 8);
#pragma unroll
            for (int g = 0; g < NGRP; ++g) {
                const int cur = g & 1, nxt = (g & 1) ^ 1;
                if (g + 1 < NGRP) {
#pragma unroll
                    for (int kk = 0; kk < GK; ++kk)
                        cb2[nxt][kk] = cload8(rhB + (size_t)rowAC * OUT +
                                              ((g + 1) * GK + kk) * 32 + quad * 8);
                }
#pragma unroll
                for (int kk = 0; kk < GK; ++kk) {
                    const int kb = g * GK + kk;
                    short8 b = *(const short8*)(Wc + (size_t)l16 * ROWB +
                                                ((KH0 * 2 + kb * 64 + quad * 16) ^ swz));
                    accC = __builtin_amdgcn_mfma_f32_16x16x32_bf16(cb2[cur][kk], b, accC, 0, 0, 0);
                }
            }
            const int col   = cgC * 16 + l16;
            const float bia = cbF[col];
            float zv[4], hov[4];
#pragma unroll
            for (int r = 0; r < 4; ++r) {
                const int row = mbC * MRC + wv * 16 + quad * 4 + r;
                zv[r] = cload_f32(zbF + (size_t)row * OUT + col);
            }
#pragma unroll
            for (int r = 0; r < 4; ++r) {
                const int row = mbC * MRC + wv * 16 + quad * 4 + r;
                hov[r] = cload_f32(hF + (size_t)row * OUT + col);
            }
#pragma unroll
            for (int r = 0; r < 4; ++r) {
                const int row = mbC * MRC + wv * 16 + quad * 4 + r;
                float c = tanhf(accC[r] + bia);
                size_t idx = (size_t)row * OUT + col;
                float hn = (t < lens[row]) ? (zv[r] * hov[r] + (1.f - zv[r]) * c) : hov[r];
                cstore_f32(hF + idx, hn);
                cstore_bf16(hB + idx, hn);
                if constexpr (WRITE_ALL)
                    Hall[(size_t)(t - t0) * 256 * OUT + idx] = f2bf(hn);
            }
        }
        if (t + 1 < t1) gates_x(t + 1);
        dev_barrier2(bar, ++epoch);
    }
}

// =================================================================
extern "C" void kernel_launch(void* const* d_in, const int* in_sizes, int n_in,
                              void* d_out, int out_size, void* d_ws, size_t ws_size,
                              hipStream_t stream)
{
    (void)in_sizes; (void)n_in; (void)out_size; (void)ws_size;

    const int*   seq  = (const int*)d_in[0];
    const int*   lens = (const int*)d_in[1];
    const float* tab  = (const float*)d_in[2];
    const float* gkF[3] = {(const float*)d_in[3], (const float*)d_in[7], (const float*)d_in[11]};
    const float* gbF[3] = {(const float*)d_in[4], (const float*)d_in[8], (const float*)d_in[12]};
    const float* ckF[3] = {(const float*)d_in[5], (const float*)d_in[9], (const float*)d_in[13]};
    const float* cbF[3] = {(const float*)d_in[6], (const float*)d_in[10], (const float*)d_in[14]};
    const float* dwF = (const float*)d_in[15];
    const float* dbF = (const float*)d_in[16];
    float* y = (float*)d_out;

    const int outs[3] = {512, 1024, 2048};

    char* w = (char*)d_ws;
    auto alloc = [&](size_t bytes) -> void* {
        void* p = (void*)w;
        w += (bytes + 255) & ~(size_t)255;
        return p;
    };

    // workspace (~56 MB)
    bf16* WgxT    = (bf16*)alloc((size_t)4096 * 1024 * sizeof(bf16));
    bf16* WcxT    = (bf16*)alloc((size_t)2048 * 1024 * sizeof(bf16));
    bf16* emb_all = (bf16*)alloc((size_t)T_ * B_ * 32 * sizeof(bf16));
    bf16* H0c     = (bf16*)alloc((size_t)CH * B_ * 512 * sizeof(bf16));
    bf16* H1c     = (bf16*)alloc((size_t)CH * B_ * 1024 * sizeof(bf16));
    float* hf[3]; bf16* hb[3]; bf16* rh[3]; float* zb[3];
    for (int l = 0; l < 3; ++l) {
        hf[l] = (float*)alloc((size_t)B_ * outs[l] * sizeof(float));
        hb[l] = (bf16*)alloc((size_t)B_ * outs[l] * sizeof(bf16));
        rh[l] = (bf16*)alloc((size_t)B_ * outs[l] * sizeof(bf16));
        zb[l] = (float*)alloc((size_t)B_ * outs[l] * sizeof(float));
    }
    bf16* dw = (bf16*)alloc((size_t)3584 * 512 * sizeof(bf16));
    bf16* db = (bf16*)alloc((size_t)512 * sizeof(bf16));
    bf16* cc = (bf16*)alloc((size_t)B_ * 3584 * sizeof(bf16));
    unsigned* bar_area = (unsigned*)alloc(12 * 1024);   // 12 slots x 1KB

    auto kL0 = gru_layer_k<32,   512,  false, true>;
    auto kL1 = gru_layer_k<512,  1024, false, true>;
    auto kL2 = gru_layer_k<1024, 2048, true,  false>;
    const unsigned lds0 = (unsigned)(2 * 16 * row_bytes(32 + 512));
    const unsigned lds1 = (unsigned)(2 * 16 * row_bytes(512 + 1024));
    const unsigned lds2 = (unsigned)(2 * 16 * row_bytes(2048));

    hipFuncSetAttribute((const void*)kL0, hipFuncAttributeMaxDynamicSharedMemorySize, (int)lds0);
    hipFuncSetAttribute((const void*)kL1, hipFuncAttributeMaxDynamicSharedMemorySize, (int)lds1);
    hipFuncSetAttribute((const void*)kL2, hipFuncAttributeMaxDynamicSharedMemorySize, (int)lds2);

    // ---- prep ----
    {
        int n8 = 3584 * 512 / 8;
        cvt_k<<<(n8 + 255) / 256, 256, 0, stream>>>(dwF, dw, n8);
        cvt_k<<<1, 256, 0, stream>>>(dbF, db, 512 / 8);
    }
    embed_k<<<T_ * B_ * 4 / 256, 256, 0, stream>>>(seq, tab, emb_all);
    transpose_bf16_k<<<dim3(1024 / 32, 4096 / 32), 256, 0, stream>>>(gkF[2], 4096, WgxT, 1024, 4096);
    transpose_bf16_k<<<dim3(1024 / 32, 2048 / 32), 256, 0, stream>>>(ckF[2], 2048, WcxT, 1024, 2048);

    for (int l = 0; l < 3; ++l) {
        hipMemsetAsync(hf[l], 0, (size_t)B_ * outs[l] * sizeof(float), stream);
        hipMemsetAsync(hb[l], 0, (size_t)B_ * outs[l] * sizeof(bf16), stream);
    }
    hipMemsetAsync(bar_area, 0, 12 * 1024, stream);

    // ---- recurrent layers: 32-step chunks, L0 -> L1 -> L2 per chunk ----
    for (int c = 0; c < T_ / CH; ++c) {
        int t0 = c * CH, t1 = t0 + CH;
        {
            const bf16* xall = emb_all;
            const float *g = gkF[0], *gb_ = gbF[0], *cw = ckF[0], *cb_ = cbF[0];
            const bf16 *wgx = nullptr, *wcx = nullptr;
            float* hf_ = hf[0]; bf16* hb_ = hb[0]; bf16* rh_ = rh[0]; float* zb_ = zb[0];
            bf16* hall = H0c; unsigned* bc = bar_area + (c * 3 + 0) * 256; int xb = 0;
            void* args[] = {&xall, &g, &gb_, &cw, &cb_, &wgx, &wcx, (void*)&lens,
                            &hf_, &hb_, &rh_, &zb_, &hall, &bc, &t0, &t1, &xb};
            hipLaunchCooperativeKernel((const void*)kL0, dim3(256), dim3(512), args, lds0, stream);
        }
        {
            const bf16* xall = H0c;
            const float *g = gkF[1], *gb_ = gbF[1], *cw = ckF[1], *cb_ = cbF[1];
            const bf16 *wgx = nullptr, *wcx = nullptr;
            float* hf_ = hf[1]; bf16* hb_ = hb[1]; bf16* rh_ = rh[1]; float* zb_ = zb[1];
            bf16* hall = H1c; unsigned* bc = bar_area + (c * 3 + 1) * 256; int xb = t0;
            void* args[] = {&xall, &g, &gb_, &cw, &cb_, &wgx, &wcx, (void*)&lens,
                            &hf_, &hb_, &rh_, &zb_, &hall, &bc, &t0, &t1, &xb};
            hipLaunchCooperativeKernel((const void*)kL1, dim3(256), dim3(512), args, lds1, stream);
        }
        {
            const bf16* xall = H1c;
            const float *g = gkF[2], *gb_ = gbF[2], *cw = ckF[2], *cb_ = cbF[2];
            const bf16 *wgx = WgxT, *wcx = WcxT;
            float* hf_ = hf[2]; bf16* hb_ = hb[2]; bf16* rh_ = rh[2]; float* zb_ = zb[2];
            bf16* hall = nullptr; unsigned* bc = bar_area + (c * 3 + 2) * 256; int xb = t0;
            void* args[] = {&xall, &g, &gb_, &cw, &cb_, &wgx, &wcx, (void*)&lens,
                            &hf_, &hb_, &rh_, &zb_, &hall, &bc, &t0, &t1, &xb};
            hipLaunchCooperativeKernel((const void*)kL2, dim3(256), dim3(512), args, lds2, stream);
        }
    }

    // ---- head ----
    concat_k<<<B_ * 3584 / 8 / 256, 256, 0, stream>>>(hf[0], hf[1], hf[2], cc);
    dense_k<<<dim3(512 / 64, 256 / 64), 256, 0, stream>>>(cc, dw, db, y);
}

// Round 7
// 17024.940 us; speedup vs baseline: 2.3332x; 1.3885x over previous
//
#include <hip/hip_runtime.h>
#include <hip/hip_bf16.h>

using bf16 = __hip_bfloat16;

typedef __attribute__((ext_vector_type(8))) short short8;
typedef __attribute__((ext_vector_type(4))) float floatx4;

static constexpr int B_ = 256;   // batch
static constexpr int T_ = 128;   // time steps
static constexpr int CH = 16;    // time-chunk (history buffers sized to this)

__device__ __forceinline__ float bf2f(bf16 v) { return __bfloat162float(v); }
__device__ __forceinline__ bf16  f2bf(float v) { return __float2bfloat16(v); }

// LDS A-stage row bytes: pad to 128B multiple so the XOR swizzle
// (flips byte bits 4..6 within a 128B stripe) stays inside the row.
constexpr int row_bytes_k(int k) { return (k * 2 + 127) & ~127; }

// ---------------- device-coherent access helpers (cross-XCD, no L2 flush) ----
__device__ __forceinline__ void cstore_f32(float* p, float v) {
    asm volatile("global_store_dword %0, %1, off sc0 sc1" :: "v"(p), "v"(v) : "memory");
}
__device__ __forceinline__ void cstore_bf16(bf16* p, float v) {
    bf16 b = f2bf(v);
    unsigned u = *(unsigned short*)&b;
    asm volatile("global_store_short %0, %1, off sc0 sc1" :: "v"(p), "v"(u) : "memory");
}
__device__ __forceinline__ float cload_f32(const float* p) {
    unsigned v = __hip_atomic_load((const unsigned*)p, __ATOMIC_RELAXED, __HIP_MEMORY_SCOPE_AGENT);
    return __uint_as_float(v);
}
__device__ __forceinline__ short8 cload8(const bf16* p) {
    union { unsigned long long q[2]; short8 v; } u;
    const unsigned long long* pp = (const unsigned long long*)p;
    u.q[0] = __hip_atomic_load(pp,     __ATOMIC_RELAXED, __HIP_MEMORY_SCOPE_AGENT);
    u.q[1] = __hip_atomic_load(pp + 1, __ATOMIC_RELAXED, __HIP_MEMORY_SCOPE_AGENT);
    return u.v;
}

// Hierarchical device-wide barrier (r5-proven): 8 group counter lines ->
// 1 root line -> read-mostly flag line; no L2 writeback/invalidate.
__device__ __forceinline__ void dev_barrier2(unsigned* bs, unsigned epoch) {
    asm volatile("s_waitcnt vmcnt(0)" ::: "memory");
    __syncthreads();
    if (threadIdx.x == 0) {
        unsigned g = blockIdx.x & 7;
        unsigned old = __hip_atomic_fetch_add(bs + g * 16, 1u,
                          __ATOMIC_RELAXED, __HIP_MEMORY_SCOPE_AGENT);
        if (old == epoch * 32u - 1u) {
            unsigned r = __hip_atomic_fetch_add(bs + 128, 1u,
                            __ATOMIC_RELAXED, __HIP_MEMORY_SCOPE_AGENT);
            if (r == epoch * 8u - 1u)
                __hip_atomic_store(bs + 144, epoch,
                                   __ATOMIC_RELAXED, __HIP_MEMORY_SCOPE_AGENT);
        }
        while (__hip_atomic_load(bs + 144, __ATOMIC_RELAXED,
                                 __HIP_MEMORY_SCOPE_AGENT) < epoch)
            __builtin_amdgcn_s_sleep(4);
        asm volatile("" ::: "memory");
    }
    __syncthreads();
}

// ---------------------------------------------------------------- fp32->bf16
__global__ __launch_bounds__(256) void cvt_k(const float* __restrict__ src,
                                             bf16* __restrict__ dst, int n8)
{
    int i = blockIdx.x * 256 + threadIdx.x;
    if (i >= n8) return;
    const float* s = src + (size_t)i * 8;
    float4 a = *(const float4*)s;
    float4 b = *(const float4*)(s + 4);
    bf16 t[8] = {f2bf(a.x), f2bf(a.y), f2bf(a.z), f2bf(a.w),
                 f2bf(b.x), f2bf(b.y), f2bf(b.z), f2bf(b.w)};
    *(uint4*)(dst + (size_t)i * 8) = *(uint4*)t;
}

// ------------------------------------------------------------------ embedding
__global__ __launch_bounds__(256) void embed_k(const int* __restrict__ seq,
                                               const float* __restrict__ tab,
                                               bf16* __restrict__ emb_all)
{
    int c = blockIdx.x * 256 + threadIdx.x;
    int t = c >> 10;
    int r = c & 1023;
    int b = r >> 2, i = r & 3;
    int tok = seq[b * T_ + t];
    const float* s = tab + (size_t)tok * 32 + i * 8;
    bf16 tmp[8];
#pragma unroll
    for (int j = 0; j < 8; ++j) tmp[j] = f2bf(s[j]);
    *(uint4*)(emb_all + ((size_t)t * B_ + b) * 32 + i * 8) = *(uint4*)tmp;
}

// ----------------------------------------------------- fp32 -> bf16 transpose
// out[n][k] = bf16(in[k][n]);  grid (K/32, N/32)
__global__ __launch_bounds__(256) void transpose_bf16_k(
    const float* __restrict__ in, int ldin, bf16* __restrict__ out, int K, int N)
{
    __shared__ float tile[32][33];
    const int bk = blockIdx.x * 32, bn = blockIdx.y * 32;
    const int tx = threadIdx.x & 31, ty = threadIdx.x >> 5;
#pragma unroll
    for (int i = 0; i < 32; i += 8)
        tile[ty + i][tx] = in[(size_t)(bk + ty + i) * ldin + (bn + tx)];
    __syncthreads();
#pragma unroll
    for (int i = 0; i < 32; i += 8)
        out[(size_t)(bn + ty + i) * K + (bk + tx)] = f2bf(tile[tx][ty + i]);
}

// ------------------------------------------------------------------- concat
__global__ __launch_bounds__(256) void concat_k(const float* __restrict__ h0,
                                                const float* __restrict__ h1,
                                                const float* __restrict__ h2,
                                                bf16* __restrict__ cc)
{
    int c = blockIdx.x * 256 + threadIdx.x;
    int b = c / 448;
    int j = (c % 448) * 8;
    const float* src;
    if (j < 512)        src = h0 + (size_t)b * 512 + j;
    else if (j < 1536)  src = h1 + (size_t)b * 1024 + (j - 512);
    else                src = h2 + (size_t)b * 2048 + (j - 1536);
    bf16 tmp[8];
#pragma unroll
    for (int i = 0; i < 8; ++i) tmp[i] = f2bf(src[i]);
    *(uint4*)(cc + (size_t)b * 3584 + j) = *(uint4*)tmp;
}

// --------------------------------------------------------------- final dense
__global__ __launch_bounds__(256) void dense_k(const bf16* __restrict__ A,
                                               const bf16* __restrict__ Bw,
                                               const bf16* __restrict__ bias,
                                               float* __restrict__ yout)
{
    __shared__ __align__(16) bf16 As[64 * 40];
    __shared__ __align__(16) bf16 Bs[64 * 40];

    const int tid  = threadIdx.x;
    const int bm   = blockIdx.y * 64;
    const int bn   = blockIdx.x * 64;
    const int lane = tid & 63;
    const int wave = tid >> 6;
    const int wm   = (wave >> 1) * 32;
    const int wn   = (wave & 1) * 32;
    const int quad = lane >> 4;
    const int l16  = lane & 15;

    floatx4 acc[2][2] = {};

    const int ar = tid >> 2, ak = (tid & 3) * 8;
    const int bk = tid >> 3, bn0 = (tid & 7) * 8;

    for (int k0 = 0; k0 < 3584; k0 += 32) {
        uint4 av = *(const uint4*)(A + (size_t)(bm + ar) * 3584 + k0 + ak);
        *(uint4*)&As[ar * 40 + ak] = av;
        uint4 bv = *(const uint4*)(Bw + (size_t)(k0 + bk) * 512 + bn + bn0);
        bf16 tmp[8];
        *(uint4*)tmp = bv;
#pragma unroll
        for (int i = 0; i < 8; ++i) Bs[(bn0 + i) * 40 + bk] = tmp[i];
        __syncthreads();

        short8 af0 = *(const short8*)&As[(wm + l16) * 40 + quad * 8];
        short8 af1 = *(const short8*)&As[(wm + 16 + l16) * 40 + quad * 8];
        short8 bw0 = *(const short8*)&Bs[(wn + l16) * 40 + quad * 8];
        short8 bw1 = *(const short8*)&Bs[(wn + 16 + l16) * 40 + quad * 8];

        acc[0][0] = __builtin_amdgcn_mfma_f32_16x16x32_bf16(af0, bw0, acc[0][0], 0, 0, 0);
        acc[0][1] = __builtin_amdgcn_mfma_f32_16x16x32_bf16(af0, bw1, acc[0][1], 0, 0, 0);
        acc[1][0] = __builtin_amdgcn_mfma_f32_16x16x32_bf16(af1, bw0, acc[1][0], 0, 0, 0);
        acc[1][1] = __builtin_amdgcn_mfma_f32_16x16x32_bf16(af1, bw1, acc[1][1], 0, 0, 0);
        __syncthreads();
    }

#pragma unroll
    for (int tm = 0; tm < 2; ++tm)
#pragma unroll
        for (int tn = 0; tn < 2; ++tn)
#pragma unroll
            for (int r = 0; r < 4; ++r) {
                const int row = bm + wm + tm * 16 + quad * 4 + r;
                const int col = bn + wn + tn * 16 + l16;
                float v = acc[tm][tn][r] + bf2f(bias[col]);
                yout[(size_t)row * 512 + col] = tanhf(v);
            }
}

// =================================================================
// Persistent GRU layer over a time chunk [t0, t1) — round-7 layout.
// 256 WGs = 16 col-groups (cg = wgid&15, XCD = wgid%8) x 16 m-bands
// (mb = wgid>>4, MR=16 rows). Each WG stages only its 16 rows of
// [x | state] into a swizzled LDS A-buffer (coherent loads for state);
// weights stream as bf16 transposed [N][K] via plain loads that stay
// resident in the WG's XCD L2 (same cg -> same cols every step).
// Phase-balanced: x-projections run in the opposite phase.
// =================================================================
template <int IN, int OUT, bool WRITE_ALL>
__global__ __launch_bounds__(512) void gru_layer_k(
    const bf16* __restrict__ Xall,   // layer input history
    const bf16* __restrict__ WgT,    // [2*OUT][IN+OUT] bf16 (transposed)
    const float* __restrict__ gbF,   // [2*OUT]
    const bf16* __restrict__ WcT,    // [OUT][IN+OUT] bf16 (transposed)
    const float* __restrict__ cbF,   // [OUT]
    const int* __restrict__ lens,
    float* __restrict__ hF,          // [256][OUT] fp32 master state
    bf16* __restrict__ hB,           // [256][OUT] bf16 state
    bf16* __restrict__ rhB,          // [256][OUT] bf16 r*h
    float* __restrict__ zbF,         // [256][OUT] fp32 z
    bf16* __restrict__ Hall,         // [t1-t0][256][OUT] (WRITE_ALL)
    unsigned* __restrict__ bar,
    int t0, int t1, int xbase)
{
    constexpr int K     = IN + OUT;
    constexpr int NG    = 2 * OUT;
    constexpr int NCOLG = NG / 16;                   // gate cols per WG
    constexpr int NFG   = NCOLG / 16;                // 16-col frags per WG
    constexpr int FPWG  = (NFG >= 8) ? NFG / 8 : 1;  // frags per wave
    constexpr int NCOLC = OUT / 16;                  // cand cols per WG
    constexpr int NFC   = NCOLC / 16;                // <= 8 always
    constexpr int ROWB  = row_bytes_k(K);

    extern __shared__ char lds[];                    // A-stage [16][ROWB]

    const int tid  = threadIdx.x;
    const int wv   = tid >> 6;
    const int lane = tid & 63;
    const int l16  = lane & 15;
    const int quad = lane >> 4;
    const int cg   = blockIdx.x & 15;
    const int mb   = blockIdx.x >> 4;
    const int rowbase = mb * 16;
    const int swz  = (l16 & 7) << 4;

    const bool actG = (wv * FPWG) < NFG;
    const bool actC = wv < NFC;

    // ---- staging: 16 rows of x / state into swizzled LDS ----
    auto stage_x = [&](int t) {
        const bf16* xb = Xall + (size_t)(t - xbase) * 256 * IN + (size_t)rowbase * IN;
        for (int idx = tid; idx < 16 * IN / 8; idx += 512) {
            const int r = idx / (IN / 8), c = idx % (IN / 8);
            uint4 v = *(const uint4*)(xb + (size_t)r * IN + c * 8);
            *(uint4*)(lds + r * ROWB + ((c * 16) ^ ((r & 7) << 4))) = v;
        }
    };
    auto stage_s = [&](const bf16* __restrict__ src) {   // -> cols [IN, K)
        const bf16* sb = src + (size_t)rowbase * OUT;
        for (int idx = tid; idx < 16 * OUT / 8; idx += 512) {
            const int r = idx / (OUT / 8), c = idx % (OUT / 8);
            short8 v = cload8(sb + (size_t)r * OUT + c * 8);
            *(short8*)(lds + r * ROWB + ((IN * 2 + c * 16) ^ ((r & 7) << 4))) = v;
        }
    };
    auto a_frag = [&](int kbyte) -> short8 {
        return *(const short8*)(lds + l16 * ROWB + ((kbyte + quad * 16) ^ swz));
    };

    floatx4 accG[FPWG];
    floatx4 accC;

    auto gates_x = [&]() {     // x-part of gates (reads LDS x-region)
        if (!actG) return;
#pragma unroll
        for (int f = 0; f < FPWG; ++f) accG[f] = (floatx4){0.f, 0.f, 0.f, 0.f};
#pragma unroll 4
        for (int kb = 0; kb < IN / 32; ++kb) {
            short8 a = a_frag(kb * 64);
#pragma unroll
            for (int f = 0; f < FPWG; ++f) {
                const int col = cg * NCOLG + (wv * FPWG + f) * 16 + l16;
                short8 b = *(const short8*)(WgT + (size_t)col * K + kb * 32 + quad * 8);
                accG[f] = __builtin_amdgcn_mfma_f32_16x16x32_bf16(a, b, accG[f], 0, 0, 0);
            }
        }
    };
    auto cand_x = [&]() {      // x-part of candidate
        if (!actC) return;
        accC = (floatx4){0.f, 0.f, 0.f, 0.f};
        const int col = cg * NCOLC + wv * 16 + l16;
#pragma unroll 4
        for (int kb = 0; kb < IN / 32; ++kb) {
            short8 a = a_frag(kb * 64);
            short8 b = *(const short8*)(WcT + (size_t)col * K + kb * 32 + quad * 8);
            accC = __builtin_amdgcn_mfma_f32_16x16x32_bf16(a, b, accC, 0, 0, 0);
        }
    };

    unsigned epoch = 0;
    stage_x(t0);
    __syncthreads();
    gates_x();

    for (int t = t0; t < t1; ++t) {
        // ================= phase G: gates-h + epilogue | cand-x(t) =========
        stage_s(hB);                 // h(t-1) -> LDS state region
        __syncthreads();
        if (actG) {
#pragma unroll 4
            for (int kb = 0; kb < OUT / 32; ++kb) {
                short8 a = a_frag(IN * 2 + kb * 64);
#pragma unroll
                for (int f = 0; f < FPWG; ++f) {
                    const int col = cg * NCOLG + (wv * FPWG + f) * 16 + l16;
                    short8 b = *(const short8*)(WgT + (size_t)col * K + IN + kb * 32 + quad * 8);
                    accG[f] = __builtin_amdgcn_mfma_f32_16x16x32_bf16(a, b, accG[f], 0, 0, 0);
                }
            }
            const bool isR = (cg * NCOLG) < OUT;     // WG-uniform
            if (isR) {
                float hpre[FPWG][4];
#pragma unroll
                for (int f = 0; f < FPWG; ++f) {
                    const int col = cg * NCOLG + (wv * FPWG + f) * 16 + l16;
#pragma unroll
                    for (int r = 0; r < 4; ++r)
                        hpre[f][r] = cload_f32(hF + (size_t)(rowbase + quad * 4 + r) * OUT + col);
                }
#pragma unroll
                for (int f = 0; f < FPWG; ++f) {
                    const int col = cg * NCOLG + (wv * FPWG + f) * 16 + l16;
                    const float bia = gbF[col];
#pragma unroll
                    for (int r = 0; r < 4; ++r) {
                        float s = 1.f / (1.f + __expf(-(accG[f][r] + bia)));
                        cstore_bf16(rhB + (size_t)(rowbase + quad * 4 + r) * OUT + col,
                                    s * hpre[f][r]);
                    }
                }
            } else {
#pragma unroll
                for (int f = 0; f < FPWG; ++f) {
                    const int col = cg * NCOLG + (wv * FPWG + f) * 16 + l16;
                    const float bia = gbF[col];
#pragma unroll
                    for (int r = 0; r < 4; ++r) {
                        float s = 1.f / (1.f + __expf(-(accG[f][r] + bia)));
                        cstore_f32(zbF + (size_t)(rowbase + quad * 4 + r) * OUT + (col - OUT), s);
                    }
                }
            }
        }
        cand_x();                    // x(t) still in LDS x-region
        dev_barrier2(bar, ++epoch);

        // ================= phase C: cand-h + epilogue | gates-x(t+1) =======
        stage_s(rhB);                // rh(t) -> LDS state region
        if (t + 1 < t1) stage_x(t + 1);
        __syncthreads();
        if (actC) {
            const int col = cg * NCOLC + wv * 16 + l16;
#pragma unroll 4
            for (int kb = 0; kb < OUT / 32; ++kb) {
                short8 a = a_frag(IN * 2 + kb * 64);
                short8 b = *(const short8*)(WcT + (size_t)col * K + IN + kb * 32 + quad * 8);
                accC = __builtin_amdgcn_mfma_f32_16x16x32_bf16(a, b, accC, 0, 0, 0);
            }
            const float bia = cbF[col];
            float zv[4], hov[4]; int ln[4];
#pragma unroll
            for (int r = 0; r < 4; ++r)
                zv[r] = cload_f32(zbF + (size_t)(rowbase + quad * 4 + r) * OUT + col);
#pragma unroll
            for (int r = 0; r < 4; ++r)
                hov[r] = cload_f32(hF + (size_t)(rowbase + quad * 4 + r) * OUT + col);
#pragma unroll
            for (int r = 0; r < 4; ++r) ln[r] = lens[rowbase + quad * 4 + r];
#pragma unroll
            for (int r = 0; r < 4; ++r) {
                const int row = rowbase + quad * 4 + r;
                float c = tanhf(accC[r] + bia);
                float hn = (t < ln[r]) ? (zv[r] * hov[r] + (1.f - zv[r]) * c) : hov[r];
                size_t idx = (size_t)row * OUT + col;
                cstore_f32(hF + idx, hn);
                cstore_bf16(hB + idx, hn);
                if constexpr (WRITE_ALL)
                    Hall[(size_t)(t - t0) * 256 * OUT + idx] = f2bf(hn);
            }
        }
        if (t + 1 < t1) gates_x();   // x(t+1) staged above
        dev_barrier2(bar, ++epoch);
    }
}

// =================================================================
extern "C" void kernel_launch(void* const* d_in, const int* in_sizes, int n_in,
                              void* d_out, int out_size, void* d_ws, size_t ws_size,
                              hipStream_t stream)
{
    (void)in_sizes; (void)n_in; (void)out_size; (void)ws_size;

    const int*   seq  = (const int*)d_in[0];
    const int*   lens = (const int*)d_in[1];
    const float* tab  = (const float*)d_in[2];
    const float* gkF[3] = {(const float*)d_in[3], (const float*)d_in[7], (const float*)d_in[11]};
    const float* gbF[3] = {(const float*)d_in[4], (const float*)d_in[8], (const float*)d_in[12]};
    const float* ckF[3] = {(const float*)d_in[5], (const float*)d_in[9], (const float*)d_in[13]};
    const float* cbF[3] = {(const float*)d_in[6], (const float*)d_in[10], (const float*)d_in[14]};
    const float* dwF = (const float*)d_in[15];
    const float* dbF = (const float*)d_in[16];
    float* y = (float*)d_out;

    const int outs[3] = {512, 1024, 2048};
    const int ins[3]  = {32, 512, 1024};

    char* w = (char*)d_ws;
    auto alloc = [&](size_t bytes) -> void* {
        void* p = (void*)w;
        w += (bytes + 255) & ~(size_t)255;
        return p;
    };

    // transposed bf16 weights, full K = IN+OUT  (~49 MB)
    bf16 *WgT[3], *WcT[3];
    for (int l = 0; l < 3; ++l) {
        WgT[l] = (bf16*)alloc((size_t)2 * outs[l] * (ins[l] + outs[l]) * sizeof(bf16));
        WcT[l] = (bf16*)alloc((size_t)outs[l] * (ins[l] + outs[l]) * sizeof(bf16));
    }
    bf16* emb_all = (bf16*)alloc((size_t)T_ * B_ * 32 * sizeof(bf16));
    bf16* H0c     = (bf16*)alloc((size_t)CH * B_ * 512 * sizeof(bf16));
    bf16* H1c     = (bf16*)alloc((size_t)CH * B_ * 1024 * sizeof(bf16));
    float* hf[3]; bf16* hb[3]; bf16* rh[3]; float* zb[3];
    for (int l = 0; l < 3; ++l) {
        hf[l] = (float*)alloc((size_t)B_ * outs[l] * sizeof(float));
        hb[l] = (bf16*)alloc((size_t)B_ * outs[l] * sizeof(bf16));
        rh[l] = (bf16*)alloc((size_t)B_ * outs[l] * sizeof(bf16));
        zb[l] = (float*)alloc((size_t)B_ * outs[l] * sizeof(float));
    }
    bf16* dw = (bf16*)alloc((size_t)3584 * 512 * sizeof(bf16));
    bf16* db = (bf16*)alloc((size_t)512 * sizeof(bf16));
    bf16* cc = (bf16*)alloc((size_t)B_ * 3584 * sizeof(bf16));
    const int nchunk = T_ / CH;
    unsigned* bar_area = (unsigned*)alloc((size_t)nchunk * 3 * 1024);

    auto kL0 = gru_layer_k<32,   512,  true>;
    auto kL1 = gru_layer_k<512,  1024, true>;
    auto kL2 = gru_layer_k<1024, 2048, false>;
    const unsigned lds0 = 16u * (unsigned)row_bytes_k(32 + 512);     // 18,432
    const unsigned lds1 = 16u * (unsigned)row_bytes_k(512 + 1024);   // 49,152
    const unsigned lds2 = 16u * (unsigned)row_bytes_k(1024 + 2048);  // 98,304

    hipFuncSetAttribute((const void*)kL0, hipFuncAttributeMaxDynamicSharedMemorySize, (int)lds0);
    hipFuncSetAttribute((const void*)kL1, hipFuncAttributeMaxDynamicSharedMemorySize, (int)lds1);
    hipFuncSetAttribute((const void*)kL2, hipFuncAttributeMaxDynamicSharedMemorySize, (int)lds2);

    // ---- prep ----
    {
        int n8 = 3584 * 512 / 8;
        cvt_k<<<(n8 + 255) / 256, 256, 0, stream>>>(dwF, dw, n8);
        cvt_k<<<1, 256, 0, stream>>>(dbF, db, 512 / 8);
    }
    embed_k<<<T_ * B_ * 4 / 256, 256, 0, stream>>>(seq, tab, emb_all);
    // full-K transposed bf16 weights
    for (int l = 0; l < 3; ++l) {
        int K = ins[l] + outs[l];
        transpose_bf16_k<<<dim3(K / 32, 2 * outs[l] / 32), 256, 0, stream>>>(
            gkF[l], 2 * outs[l], WgT[l], K, 2 * outs[l]);
        transpose_bf16_k<<<dim3(K / 32, outs[l] / 32), 256, 0, stream>>>(
            ckF[l], outs[l], WcT[l], K, outs[l]);
    }

    for (int l = 0; l < 3; ++l) {
        hipMemsetAsync(hf[l], 0, (size_t)B_ * outs[l] * sizeof(float), stream);
        hipMemsetAsync(hb[l], 0, (size_t)B_ * outs[l] * sizeof(bf16), stream);
    }
    hipMemsetAsync(bar_area, 0, (size_t)nchunk * 3 * 1024, stream);

    // ---- recurrent layers: CH-step chunks, L0 -> L1 -> L2 per chunk ----
    for (int c = 0; c < nchunk; ++c) {
        int t0 = c * CH, t1 = t0 + CH;
        {
            const bf16* xall = emb_all; const bf16 *wg = WgT[0], *wc = WcT[0];
            const float *gb_ = gbF[0], *cb_ = cbF[0];
            float* hf_ = hf[0]; bf16* hb_ = hb[0]; bf16* rh_ = rh[0]; float* zb_ = zb[0];
            bf16* hall = H0c; unsigned* bc = bar_area + (c * 3 + 0) * 256; int xb = 0;
            void* args[] = {&xall, &wg, &gb_, &wc, &cb_, (void*)&lens,
                            &hf_, &hb_, &rh_, &zb_, &hall, &bc, &t0, &t1, &xb};
            hipLaunchCooperativeKernel((const void*)kL0, dim3(256), dim3(512), args, lds0, stream);
        }
        {
            const bf16* xall = H0c; const bf16 *wg = WgT[1], *wc = WcT[1];
            const float *gb_ = gbF[1], *cb_ = cbF[1];
            float* hf_ = hf[1]; bf16* hb_ = hb[1]; bf16* rh_ = rh[1]; float* zb_ = zb[1];
            bf16* hall = H1c; unsigned* bc = bar_area + (c * 3 + 1) * 256; int xb = t0;
            void* args[] = {&xall, &wg, &gb_, &wc, &cb_, (void*)&lens,
                            &hf_, &hb_, &rh_, &zb_, &hall, &bc, &t0, &t1, &xb};
            hipLaunchCooperativeKernel((const void*)kL1, dim3(256), dim3(512), args, lds1, stream);
        }
        {
            const bf16* xall = H1c; const bf16 *wg = WgT[2], *wc = WcT[2];
            const float *gb_ = gbF[2], *cb_ = cbF[2];
            float* hf_ = hf[2]; bf16* hb_ = hb[2]; bf16* rh_ = rh[2]; float* zb_ = zb[2];
            bf16* hall = nullptr; unsigned* bc = bar_area + (c * 3 + 2) * 256; int xb = t0;
            void* args[] = {&xall, &wg, &gb_, &wc, &cb_, (void*)&lens,
                            &hf_, &hb_, &rh_, &zb_, &hall, &bc, &t0, &t1, &xb};
            hipLaunchCooperativeKernel((const void*)kL2, dim3(256), dim3(512), args, lds2, stream);
        }
    }

    // ---- head ----
    concat_k<<<B_ * 3584 / 8 / 256, 256, 0, stream>>>(hf[0], hf[1], hf[2], cc);
    dense_k<<<dim3(512 / 64, 256 / 64), 256, 0, stream>>>(cc, dw, db, y);
}